// Round 9
// baseline (741.956 us; speedup 1.0000x reference)
//
#include <hip/hip_runtime.h>

#define N_NODES 100000
#define N_EDGES 1600000
#define DF 128
#define NL 3
#define NG 128
#define NC 2
#define BN_EPS 1e-5f
#define GEMM_BLOCKS ((N_NODES + 127) / 128)   // 782
#define SCAN_BLOCK 1024
#define SCAN_NBLK ((N_NODES + SCAN_BLOCK - 1) / SCAN_BLOCK)  // 98
#define GE_SLICES 16
#define NXCD 8
#define NODES_PER_XCD (N_NODES / NXCD)        // 12500
#define CSR_SLICES 256                        // blocks per XCD-group (2048 total = full occupancy)
#define N_QUADS (N_EDGES / 4)                 // 400000

typedef unsigned int u32;
typedef unsigned short u16;
typedef unsigned long long u64;

using bf16x8 = __attribute__((ext_vector_type(8))) short;
using f32x4  = __attribute__((ext_vector_type(4))) float;

__device__ __forceinline__ u16 f2bf(float f) {
    u32 u = __float_as_uint(f);
    u32 r = (u + 0x7FFFu + ((u >> 16) & 1u)) >> 16;
    return (u16)r;
}
__device__ __forceinline__ float bflo(u32 v) { return __uint_as_float(v << 16); }
__device__ __forceinline__ float bfhi(u32 v) { return __uint_as_float(v & 0xFFFF0000u); }

// ---------------- fp32 x -> row-major bf16 mirror ----------------
__global__ __launch_bounds__(256) void cvt_x_kernel(const float* __restrict__ x,
                                                    u16* __restrict__ xb) {
    size_t i4 = (size_t)blockIdx.x * 256 + threadIdx.x;   // one float4 / thread
    float4 v = ((const float4*)x)[i4];
    u32 lo = (u32)f2bf(v.x) | ((u32)f2bf(v.y) << 16);
    u32 hi = (u32)f2bf(v.z) | ((u32)f2bf(v.w) << 16);
    ((uint2*)xb)[i4] = make_uint2(lo, hi);
}

// ---------------- CSR build (XCD-localized dst-range passes) ----------------
// blockIdx.x & 7 selects the XCD group; each group handles only dst in its private
// 12500-node range so the atomic/scatter targets (deg 50KB, adj window ~800KB) stay
// L2-resident. Streaming dst/src reads use NON-TEMPORAL loads so they don't evict
// the partially-filled adj lines (this was the 16x write-amplification source).
__global__ __launch_bounds__(256) void count_deg_kernel(const int* __restrict__ dst,
                                                        int* __restrict__ deg) {
    int p = blockIdx.x & (NXCD - 1);
    int slice = blockIdx.x >> 3;
    int lo = p * NODES_PER_XCD, hi = lo + NODES_PER_XCD;
    const u64* d64 = (const u64*)dst;
    for (int q = slice * 256 + threadIdx.x; q < N_QUADS; q += CSR_SLICES * 256) {
        u64 w0 = __builtin_nontemporal_load(d64 + 2 * (size_t)q);
        u64 w1 = __builtin_nontemporal_load(d64 + 2 * (size_t)q + 1);
        int d0 = (int)(w0 & 0xFFFFFFFFu), d1 = (int)(w0 >> 32);
        int d2 = (int)(w1 & 0xFFFFFFFFu), d3 = (int)(w1 >> 32);
        if (d0 >= lo && d0 < hi) atomicAdd(&deg[d0], 1);
        if (d1 >= lo && d1 < hi) atomicAdd(&deg[d1], 1);
        if (d2 >= lo && d2 < hi) atomicAdd(&deg[d2], 1);
        if (d3 >= lo && d3 < hi) atomicAdd(&deg[d3], 1);
    }
}

// cursor is pre-filled with offsets (D2D copy), so the atomic returns the absolute slot.
__global__ __launch_bounds__(256) void fill_adj_kernel(const int* __restrict__ src,
                                                       const int* __restrict__ dst,
                                                       int* __restrict__ cursor,
                                                       int* __restrict__ adj) {
    int p = blockIdx.x & (NXCD - 1);
    int slice = blockIdx.x >> 3;
    int lo = p * NODES_PER_XCD, hi = lo + NODES_PER_XCD;
    const u64* d64 = (const u64*)dst;
    for (int q = slice * 256 + threadIdx.x; q < N_QUADS; q += CSR_SLICES * 256) {
        u64 w0 = __builtin_nontemporal_load(d64 + 2 * (size_t)q);
        u64 w1 = __builtin_nontemporal_load(d64 + 2 * (size_t)q + 1);
        int d0 = (int)(w0 & 0xFFFFFFFFu), d1 = (int)(w0 >> 32);
        int d2 = (int)(w1 & 0xFFFFFFFFu), d3 = (int)(w1 >> 32);
        int e = q * 4;
        if (d0 >= lo && d0 < hi) {
            int pos = atomicAdd(&cursor[d0], 1);
            adj[pos] = __builtin_nontemporal_load(src + e + 0);
        }
        if (d1 >= lo && d1 < hi) {
            int pos = atomicAdd(&cursor[d1], 1);
            adj[pos] = __builtin_nontemporal_load(src + e + 1);
        }
        if (d2 >= lo && d2 < hi) {
            int pos = atomicAdd(&cursor[d2], 1);
            adj[pos] = __builtin_nontemporal_load(src + e + 2);
        }
        if (d3 >= lo && d3 < hi) {
            int pos = atomicAdd(&cursor[d3], 1);
            adj[pos] = __builtin_nontemporal_load(src + e + 3);
        }
    }
}

__global__ __launch_bounds__(SCAN_BLOCK) void scan1_kernel(const int* __restrict__ deg,
                                                           int* __restrict__ incl,
                                                           int* __restrict__ bsum) {
    __shared__ int buf[SCAN_BLOCK];
    int t = threadIdx.x;
    int i = blockIdx.x * SCAN_BLOCK + t;
    int v = (i < N_NODES) ? deg[i] : 0;
    buf[t] = v;
    __syncthreads();
    for (int off = 1; off < SCAN_BLOCK; off <<= 1) {
        int tv = (t >= off) ? buf[t - off] : 0;
        __syncthreads();
        buf[t] += tv;
        __syncthreads();
    }
    if (i < N_NODES) incl[i] = buf[t];
    if (t == SCAN_BLOCK - 1) bsum[blockIdx.x] = buf[t];
}

__global__ __launch_bounds__(128) void scan2_kernel(const int* __restrict__ bsum,
                                                    int* __restrict__ bpre) {
    __shared__ int buf[128];
    int t = threadIdx.x;
    int v = (t < SCAN_NBLK) ? bsum[t] : 0;
    buf[t] = v;
    __syncthreads();
    for (int off = 1; off < 128; off <<= 1) {
        int tv = (t >= off) ? buf[t - off] : 0;
        __syncthreads();
        buf[t] += tv;
        __syncthreads();
    }
    if (t < SCAN_NBLK) bpre[t] = buf[t] - v;
    if (t == 127) bpre[SCAN_NBLK] = buf[127];
}

__global__ __launch_bounds__(SCAN_BLOCK) void scan3_kernel(const int* __restrict__ incl,
                                                           const int* __restrict__ deg,
                                                           const int* __restrict__ bpre,
                                                           int* __restrict__ offsets) {
    int i = blockIdx.x * SCAN_BLOCK + threadIdx.x;
    if (i < N_NODES) offsets[i] = bpre[blockIdx.x] + incl[i] - deg[i];
    if (blockIdx.x == 0 && threadIdx.x == 0) offsets[N_NODES] = bpre[SCAN_NBLK];
}

// ---------------- aggregation: one wave per node, 8-deep unrolled gathers ----------------
__global__ __launch_bounds__(256) void agg_kernel(const u32* __restrict__ X,
                                                  const int* __restrict__ offsets,
                                                  const int* __restrict__ adj,
                                                  u32* __restrict__ out) {
    int node = blockIdx.x * 4 + (threadIdx.x >> 6);
    int l = threadIdx.x & 63;                    // lane handles 2 features (u32)
    const u32* Xl = X + l;
    u32 v = Xl[(size_t)node << 6];
    float s0 = bflo(v), s1 = bfhi(v);
    float t0 = 0.f, t1 = 0.f;
    int k = offsets[node], e = offsets[node + 1];
    for (; k + 8 <= e; k += 8) {
        int a0 = adj[k + 0], a1 = adj[k + 1], a2 = adj[k + 2], a3 = adj[k + 3];
        int a4 = adj[k + 4], a5 = adj[k + 5], a6 = adj[k + 6], a7 = adj[k + 7];
        u32 u0 = Xl[(size_t)a0 << 6];
        u32 u1 = Xl[(size_t)a1 << 6];
        u32 u2 = Xl[(size_t)a2 << 6];
        u32 u3 = Xl[(size_t)a3 << 6];
        u32 u4 = Xl[(size_t)a4 << 6];
        u32 u5 = Xl[(size_t)a5 << 6];
        u32 u6 = Xl[(size_t)a6 << 6];
        u32 u7 = Xl[(size_t)a7 << 6];
        s0 += bflo(u0); s1 += bfhi(u0);
        t0 += bflo(u1); t1 += bfhi(u1);
        s0 += bflo(u2); s1 += bfhi(u2);
        t0 += bflo(u3); t1 += bfhi(u3);
        s0 += bflo(u4); s1 += bfhi(u4);
        t0 += bflo(u5); t1 += bfhi(u5);
        s0 += bflo(u6); s1 += bfhi(u6);
        t0 += bflo(u7); t1 += bfhi(u7);
    }
    if (k + 4 <= e) {
        int a0 = adj[k + 0], a1 = adj[k + 1], a2 = adj[k + 2], a3 = adj[k + 3];
        u32 u0 = Xl[(size_t)a0 << 6];
        u32 u1 = Xl[(size_t)a1 << 6];
        u32 u2 = Xl[(size_t)a2 << 6];
        u32 u3 = Xl[(size_t)a3 << 6];
        s0 += bflo(u0); s1 += bfhi(u0);
        t0 += bflo(u1); t1 += bfhi(u1);
        s0 += bflo(u2); s1 += bfhi(u2);
        t0 += bflo(u3); t1 += bfhi(u3);
        k += 4;
    }
    for (; k < e; k++) {
        u32 u = Xl[(size_t)adj[k] << 6];
        s0 += bflo(u); s1 += bfhi(u);
    }
    out[((size_t)node << 6) + l] = (u32)f2bf(s0 + t0) | ((u32)f2bf(s1 + t1) << 16);
}

// ---------------- bf16 MFMA GEMM: out[N x 128] = A[N x 128] @ W^T + bias ----------------
// Wt: bf16 transposed [col][k]. A row-major bf16. Fuses per-block BN column stats.
template <int OUT_BF16>
__global__ __launch_bounds__(256) void gemm_mfma_kernel(const u16* __restrict__ A,
                                                        const u16* __restrict__ Wt,
                                                        const float* __restrict__ bias,
                                                        void* __restrict__ outp,
                                                        float* __restrict__ psum,
                                                        float* __restrict__ psq, int nrows) {
    __shared__ __align__(16) u16 sA[16384];  // [row][k] swizzled, 32 KB
    __shared__ __align__(16) u16 sW[16384];  // [col][k] swizzled, 32 KB

    int tid = threadIdx.x;
    int rb = blockIdx.x * 128;

    // stage W
    {
        const uint4* g = (const uint4*)Wt;
#pragma unroll
        for (int p = 0; p < 8; p++) {
            int q = p * 256 + tid;
            int r = q >> 4, seg = q & 15;
            uint4 v = g[q];
            *(uint4*)((char*)sW + r * 256 + ((seg * 16) ^ ((r & 7) << 4))) = v;
        }
    }
    // stage A tile (128 rows)
    {
#pragma unroll
        for (int p = 0; p < 8; p++) {
            int q = p * 256 + tid;
            int r = q >> 4, seg = q & 15;
            int grow = rb + r;
            uint4 v = make_uint4(0, 0, 0, 0);
            if (grow < nrows) v = *(const uint4*)(A + (size_t)grow * 128 + seg * 8);
            *(uint4*)((char*)sA + r * 256 + ((seg * 16) ^ ((r & 7) << 4))) = v;
        }
    }
    __syncthreads();

    int l = tid & 63, w = tid >> 6;
    int lr = l & 15, lg = l >> 4;

    f32x4 acc[2][8];
#pragma unroll
    for (int t = 0; t < 2; t++)
#pragma unroll
        for (int c = 0; c < 8; c++) acc[t][c] = (f32x4){0.f, 0.f, 0.f, 0.f};

#pragma unroll
    for (int kc = 0; kc < 4; kc++) {
        int kb2 = (kc * 32 + lg * 8) * 2;   // byte offset along k
        bf16x8 a[2], b[8];
#pragma unroll
        for (int t = 0; t < 2; t++) {
            int row = w * 32 + t * 16 + lr;
            a[t] = *(const bf16x8*)((const char*)sA + row * 256 + (kb2 ^ ((row & 7) << 4)));
        }
#pragma unroll
        for (int c = 0; c < 8; c++) {
            int col = c * 16 + lr;
            b[c] = *(const bf16x8*)((const char*)sW + col * 256 + (kb2 ^ ((col & 7) << 4)));
        }
#pragma unroll
        for (int t = 0; t < 2; t++)
#pragma unroll
            for (int c = 0; c < 8; c++)
                acc[t][c] = __builtin_amdgcn_mfma_f32_16x16x32_bf16(a[t], b[c], acc[t][c], 0, 0, 0);
    }

    // epilogue: bias add, store, per-lane column stats
    float bb[8];
#pragma unroll
    for (int c = 0; c < 8; c++) bb[c] = bias[c * 16 + lr];

    float sp[8], qp[8];
#pragma unroll
    for (int c = 0; c < 8; c++) { sp[c] = 0.f; qp[c] = 0.f; }

    float* outF = (float*)outp;
    u16* outB = (u16*)outp;
#pragma unroll
    for (int t = 0; t < 2; t++) {
#pragma unroll
        for (int r = 0; r < 4; r++) {
            int grow = rb + w * 32 + t * 16 + lg * 4 + r;
            bool ok = grow < nrows;
#pragma unroll
            for (int c = 0; c < 8; c++) {
                float v = acc[t][c][r] + bb[c];
                if (ok) {
                    int col = c * 16 + lr;
                    if (OUT_BF16)
                        outB[(size_t)grow * 128 + col] = f2bf(v);
                    else
                        outF[(size_t)grow * 128 + col] = v;
                    sp[c] += v;
                    qp[c] += v * v;
                }
            }
        }
    }
#pragma unroll
    for (int c = 0; c < 8; c++) {
        sp[c] += __shfl_xor(sp[c], 16); sp[c] += __shfl_xor(sp[c], 32);
        qp[c] += __shfl_xor(qp[c], 16); qp[c] += __shfl_xor(qp[c], 32);
    }
    __syncthreads();                 // sA no longer read; reuse as reduction buffer
    float* sred = (float*)sA;        // [w][c][lr][2]
    if (lg == 0) {
#pragma unroll
        for (int c = 0; c < 8; c++) {
            sred[(((w * 8 + c) * 16) + lr) * 2 + 0] = sp[c];
            sred[(((w * 8 + c) * 16) + lr) * 2 + 1] = qp[c];
        }
    }
    __syncthreads();
    if (tid < 128) {
        int c = tid >> 4, r = tid & 15;
        float s = 0.f, q = 0.f;
#pragma unroll
        for (int ww = 0; ww < 4; ww++) {
            s += sred[(((ww * 8 + c) * 16) + r) * 2 + 0];
            q += sred[(((ww * 8 + c) * 16) + r) * 2 + 1];
        }
        psum[blockIdx.x * 128 + tid] = s;
        psq[blockIdx.x * 128 + tid] = q;
    }
}

// ---------------- BN finalize (1 block, 1024 thr) ----------------
// MODE 0: scale = rsqrt(v+eps)*g ; shift = bt - m*scale
// MODE 1: r2=rsqrt(v+eps); a=r2*g; vu=v*a*a; r3=rsqrt(vu+eps); scale=a*r3*og; shift=ob-m*scale
template <int MODE>
__global__ __launch_bounds__(1024) void bnfin_kernel(const float* __restrict__ psum,
                                                     const float* __restrict__ psq,
                                                     const float* __restrict__ g,
                                                     const float* __restrict__ bt,
                                                     const float* __restrict__ og,
                                                     const float* __restrict__ ob,
                                                     float* __restrict__ scale,
                                                     float* __restrict__ shift) {
    __shared__ float ss[8][128], qq[8][128];
    int t = threadIdx.x;
    int f = t & 127, grp = t >> 7;
    float s = 0.f, q = 0.f;
    for (int b = grp; b < GEMM_BLOCKS; b += 8) {
        s += psum[b * 128 + f];
        q += psq[b * 128 + f];
    }
    ss[grp][f] = s; qq[grp][f] = q;
    __syncthreads();
    if (t < 128) {
        float S = 0.f, Q = 0.f;
#pragma unroll
        for (int i = 0; i < 8; i++) { S += ss[i][f]; Q += qq[i][f]; }
        float m = S / (float)N_NODES;
        float v = Q / (float)N_NODES - m * m;
        if (v < 0.f) v = 0.f;
        float sc, sh;
        if (MODE == 0) {
            float r = rsqrtf(v + BN_EPS);
            sc = r * g[f];
            sh = bt[f] - m * sc;
        } else {
            float r2 = rsqrtf(v + BN_EPS);
            float a = r2 * g[f];
            float vu = v * a * a;
            float r3 = rsqrtf(vu + BN_EPS);
            sc = a * r3 * og[f];
            sh = ob[f] - m * sc;
        }
        scale[f] = sc;
        shift[f] = sh;
    }
}

// ---------------- W2 fold (parallel, 128 blocks x 128 thr) ----------------
// W2ft[j][k] = bf16(sc1[k]*W2[k][j]);  b2f[j] = b2[j] + sum_k sh1[k]*W2[k][j]
__global__ __launch_bounds__(128) void foldw2_kernel(const float* __restrict__ W2,
                                                     const float* __restrict__ b2,
                                                     const float* __restrict__ sc1,
                                                     const float* __restrict__ sh1,
                                                     u16* __restrict__ W2ft,
                                                     float* __restrict__ b2f) {
    int j = blockIdx.x;
    int k = threadIdx.x;
    float w = W2[k * 128 + j];
    W2ft[j * 128 + k] = f2bf(sc1[k] * w);
    float p = sh1[k] * w;
#pragma unroll
    for (int off = 1; off < 64; off <<= 1) p += __shfl_xor(p, off);
    __shared__ float r2[2];
    if ((k & 63) == 0) r2[k >> 6] = p;
    __syncthreads();
    if (k == 0) b2f[j] = b2[j] + r2[0] + r2[1];
}

// ---------------- weight prep: all layers at once ----------------
__global__ void w1_prep_kernel(const float* __restrict__ W, u16* __restrict__ Wt) {
    int q = blockIdx.x * 256 + threadIdx.x;   // 192 blocks x 256 = 3*16384
    int layer = q >> 14;
    int r = q & 16383;
    int j = r >> 7, k = r & 127;
    Wt[q] = f2bf(W[layer * 16384 + k * 128 + j]);
}

// ---------------- relu-affine, bf16 in -> bf16 out (layers 0..L-2) ----------------
__global__ __launch_bounds__(256) void relu_affine_bf16_kernel(const u16* __restrict__ Hb,
                                                               const float* __restrict__ scale,
                                                               const float* __restrict__ shift,
                                                               u16* __restrict__ xb) {
    size_t i4 = (size_t)blockIdx.x * 256 + threadIdx.x;   // 4 bf16 / thread
    int fb = ((int)(i4 & 31)) * 4;
    uint2 hv = ((const uint2*)Hb)[i4];
    float4 sc = *(const float4*)&scale[fb];
    float4 sh = *(const float4*)&shift[fb];
    float y0 = fmaxf(bflo(hv.x) * sc.x + sh.x, 0.f);
    float y1 = fmaxf(bfhi(hv.x) * sc.y + sh.y, 0.f);
    float y2 = fmaxf(bflo(hv.y) * sc.z + sh.z, 0.f);
    float y3 = fmaxf(bfhi(hv.y) * sc.w + sh.w, 0.f);
    u32 lo = (u32)f2bf(y0) | ((u32)f2bf(y1) << 16);
    u32 hi = (u32)f2bf(y2) | ((u32)f2bf(y3) << 16);
    ((uint2*)xb)[i4] = make_uint2(lo, hi);
}

// ---------------- relu-affine, final layer: fp32 in-place ----------------
__global__ __launch_bounds__(256) void relu_affine_final_kernel(float* __restrict__ H,
                                                                const float* __restrict__ scale,
                                                                const float* __restrict__ shift) {
    size_t i4 = (size_t)blockIdx.x * 256 + threadIdx.x;
    int fb = ((int)(i4 & 31)) * 4;
    float4 h = ((const float4*)H)[i4];
    float4 sc = *(const float4*)&scale[fb];
    float4 sh = *(const float4*)&shift[fb];
    float4 y;
    y.x = fmaxf(h.x * sc.x + sh.x, 0.f);
    y.y = fmaxf(h.y * sc.y + sh.y, 0.f);
    y.z = fmaxf(h.z * sc.z + sh.z, 0.f);
    y.w = fmaxf(h.w * sc.w + sh.w, 0.f);
    ((float4*)H)[i4] = y;
}

// ---------------- readout ----------------
__global__ __launch_bounds__(128) void graph_embed_part_kernel(const float* __restrict__ X,
                                                               const float* __restrict__ w,
                                                               const int* __restrict__ batch,
                                                               float* __restrict__ gpart) {
    int g = blockIdx.x;
    int sl = blockIdx.y;
    int f = threadIdx.x;
    int lo = 0, hi = N_NODES;
    while (lo < hi) { int mid = (lo + hi) >> 1; if (batch[mid] < g) lo = mid + 1; else hi = mid; }
    int s = lo;
    lo = 0; hi = N_NODES;
    while (lo < hi) { int mid = (lo + hi) >> 1; if (batch[mid] < g + 1) lo = mid + 1; else hi = mid; }
    int e = lo;
    int cnt = e - s;
    int per = (cnt + GE_SLICES - 1) / GE_SLICES;
    int rs = s + sl * per;
    int re = rs + per; if (re > e) re = e;
    float acc = 0.f;
    for (int r = rs; r < re; r++) acc += X[(size_t)r * DF + f] * w[r];
    gpart[((size_t)g * GE_SLICES + sl) * DF + f] = acc;
}

__global__ __launch_bounds__(128) void graph_embed_reduce_kernel(const float* __restrict__ gpart,
                                                                 float* __restrict__ ge) {
    int g = blockIdx.x, f = threadIdx.x;
    float a = 0.f;
#pragma unroll
    for (int s = 0; s < GE_SLICES; s++) a += gpart[((size_t)g * GE_SLICES + s) * DF + f];
    ge[g * DF + f] = a;
}

__global__ void final_fc_kernel(const float* __restrict__ ge, const float* __restrict__ fcW,
                                const float* __restrict__ fcb, float* __restrict__ out) {
    int idx = blockIdx.x * blockDim.x + threadIdx.x;  // G*C = 256
    if (idx < NG * NC) {
        int g = idx / NC, c = idx % NC;
        float acc = fcb[c];
        for (int d = 0; d < DF; d++) acc += ge[g * DF + d] * fcW[d * NC + c];
        out[idx] = acc;
    }
}

// ---------------- launcher ----------------
extern "C" void kernel_launch(void* const* d_in, const int* in_sizes, int n_in,
                              void* d_out, int out_size, void* d_ws, size_t ws_size,
                              hipStream_t stream) {
    const float* x    = (const float*)d_in[0];
    const int*   ei   = (const int*)d_in[1];
    const int*   src  = ei;
    const int*   dst  = ei + N_EDGES;
    const float* nw   = (const float*)d_in[2];
    const int*   batch= (const int*)d_in[3];
    const float* W1   = (const float*)d_in[4];
    const float* b1   = (const float*)d_in[5];
    const float* g1   = (const float*)d_in[6];
    const float* bt1  = (const float*)d_in[7];
    const float* W2   = (const float*)d_in[8];
    const float* b2   = (const float*)d_in[9];
    const float* g2   = (const float*)d_in[10];
    const float* bt2  = (const float*)d_in[11];
    const float* og   = (const float*)d_in[12];
    const float* ob   = (const float*)d_in[13];
    const float* fcW  = (const float*)d_in[14];
    const float* fcb  = (const float*)d_in[15];

    float* out_f    = (float*)d_out;
    float* node_out = out_f;                              // N*DF fp32
    float* ge       = out_f + (size_t)N_NODES * DF;       // G*DF
    float* cls      = ge + NG * DF;                       // G*C

    char* w = (char*)d_ws;
    auto alloc = [&](size_t bytes) { char* p = w; w += (bytes + 255) & ~(size_t)255; return p; };

    u16*   XB      = (u16*)alloc((size_t)N_NODES * DF * 2);     // row-major bf16 features
    u16*   AGG     = (u16*)alloc((size_t)N_NODES * DF * 2);     // bf16 agg output / bf16 h2
    u16*   H1      = (u16*)alloc((size_t)N_NODES * DF * 2);     // bf16 h1_raw
    int*   deg     = (int*)alloc((size_t)N_NODES * 4);
    int*   cursor  = (int*)alloc((size_t)N_NODES * 4);
    int*   offsets = (int*)alloc((size_t)(N_NODES + 1) * 4);
    int*   incl    = (int*)alloc((size_t)N_NODES * 4);
    int*   bsum    = (int*)alloc((SCAN_NBLK + 1) * 4);
    int*   bpre    = (int*)alloc((SCAN_NBLK + 1) * 4);
    int*   adj     = (int*)alloc((size_t)N_EDGES * 4);
    float* psum    = (float*)alloc((size_t)GEMM_BLOCKS * 128 * 4);
    float* psq     = (float*)alloc((size_t)GEMM_BLOCKS * 128 * 4);
    u16*   W1t     = (u16*)alloc((size_t)NL * 16384 * 2);
    u16*   W2ft    = (u16*)alloc(16384 * 2);
    float* b2f     = (float*)alloc(128 * 4);
    float* sc1     = (float*)alloc(128 * 4);
    float* sh1     = (float*)alloc(128 * 4);
    float* scaleO  = (float*)alloc(128 * 4);
    float* shiftO  = (float*)alloc(128 * 4);
    float* gpart   = (float*)alloc((size_t)NG * GE_SLICES * DF * 4);

    // bf16 mirror of input x + weight transposes
    cvt_x_kernel<<<12500, 256, 0, stream>>>(x, XB);
    w1_prep_kernel<<<192, 256, 0, stream>>>(W1, W1t);

    // CSR build (XCD-localized, nt-streamed, full occupancy)
    hipMemsetAsync(deg, 0, (size_t)N_NODES * 4, stream);
    count_deg_kernel<<<NXCD * CSR_SLICES, 256, 0, stream>>>(dst, deg);
    scan1_kernel<<<SCAN_NBLK, SCAN_BLOCK, 0, stream>>>(deg, incl, bsum);
    scan2_kernel<<<1, 128, 0, stream>>>(bsum, bpre);
    scan3_kernel<<<SCAN_NBLK, SCAN_BLOCK, 0, stream>>>(incl, deg, bpre, offsets);
    // cursor starts at offsets -> fill_adj atomic returns absolute slot
    hipMemcpyAsync(cursor, offsets, (size_t)N_NODES * 4, hipMemcpyDeviceToDevice, stream);
    fill_adj_kernel<<<NXCD * CSR_SLICES, 256, 0, stream>>>(src, dst, cursor, adj);

    for (int l = 0; l < NL; l++) {
        // agg = X + sum_{in-edges} X[src]   (bf16 row-major, MLP-unrolled)
        agg_kernel<<<N_NODES / 4, 256, 0, stream>>>((const u32*)XB, offsets, adj, (u32*)AGG);
        // h1_raw = agg @ W1 + b1 (bf16 out) + fused BN1 stats
        gemm_mfma_kernel<1><<<GEMM_BLOCKS, 256, 0, stream>>>(AGG, W1t + (size_t)l * 16384,
                                                             b1 + l * DF, H1, psum, psq, N_NODES);
        // BN1 finalize, then parallel fold into W2
        bnfin_kernel<0><<<1, 1024, 0, stream>>>(psum, psq, g1 + l * DF, bt1 + l * DF,
                                                nullptr, nullptr, sc1, sh1);
        foldw2_kernel<<<128, 128, 0, stream>>>(W2 + (size_t)l * DF * DF, b2 + l * DF,
                                               sc1, sh1, W2ft, b2f);
        // h2_raw = h1_raw @ W2f + b2f (+ fused stats); bf16 for l<2, fp32 for final
        if (l < NL - 1) {
            gemm_mfma_kernel<1><<<GEMM_BLOCKS, 256, 0, stream>>>(H1, W2ft, b2f, AGG,
                                                                 psum, psq, N_NODES);
        } else {
            gemm_mfma_kernel<0><<<GEMM_BLOCKS, 256, 0, stream>>>(H1, W2ft, b2f, node_out,
                                                                 psum, psq, N_NODES);
        }
        bnfin_kernel<1><<<1, 1024, 0, stream>>>(psum, psq, g2 + l * DF, bt2 + l * DF,
                                                og + l * DF, ob + l * DF, scaleO, shiftO);
        if (l < NL - 1) {
            relu_affine_bf16_kernel<<<12500, 256, 0, stream>>>(AGG, scaleO, shiftO, XB);
        } else {
            relu_affine_final_kernel<<<12500, 256, 0, stream>>>(node_out, scaleO, shiftO);
        }
    }

    graph_embed_part_kernel<<<dim3(NG, GE_SLICES), 128, 0, stream>>>(node_out, nw, batch, gpart);
    graph_embed_reduce_kernel<<<NG, 128, 0, stream>>>(gpart, ge);
    final_fc_kernel<<<1, 256, 0, stream>>>(ge, fcW, fcb, cls);
}

// Round 10
// 712.963 us; speedup vs baseline: 1.0407x; 1.0407x over previous
//
#include <hip/hip_runtime.h>

#define N_NODES 100000
#define N_EDGES 1600000
#define DF 128
#define NL 3
#define NG 128
#define NC 2
#define BN_EPS 1e-5f
#define GEMM_BLOCKS ((N_NODES + 127) / 128)   // 782
#define SCAN_BLOCK 1024
#define SCAN_NBLK ((N_NODES + SCAN_BLOCK - 1) / SCAN_BLOCK)  // 98
#define GE_SLICES 16

// ---- bucket sort params ----
#define NBKT 98                               // dst >> 10  -> 0..97
#define NBIN_BLOCKS 512
#define EDGES_PER_BLOCK (N_EDGES / NBIN_BLOCKS)  // 3125

typedef unsigned int u32;
typedef unsigned short u16;
typedef unsigned long long u64;

using bf16x8 = __attribute__((ext_vector_type(8))) short;
using f32x4  = __attribute__((ext_vector_type(4))) float;

__device__ __forceinline__ u16 f2bf(float f) {
    u32 u = __float_as_uint(f);
    u32 r = (u + 0x7FFFu + ((u >> 16) & 1u)) >> 16;
    return (u16)r;
}
__device__ __forceinline__ float bflo(u32 v) { return __uint_as_float(v << 16); }
__device__ __forceinline__ float bfhi(u32 v) { return __uint_as_float(v & 0xFFFF0000u); }

// ---------------- fp32 x -> row-major bf16 mirror ----------------
__global__ __launch_bounds__(256) void cvt_x_kernel(const float* __restrict__ x,
                                                    u16* __restrict__ xb) {
    size_t i4 = (size_t)blockIdx.x * 256 + threadIdx.x;   // one float4 / thread
    float4 v = ((const float4*)x)[i4];
    u32 lo = (u32)f2bf(v.x) | ((u32)f2bf(v.y) << 16);
    u32 hi = (u32)f2bf(v.z) | ((u32)f2bf(v.w) << 16);
    ((uint2*)xb)[i4] = make_uint2(lo, hi);
}

// ---------------- CSR build via 2-level bucket sort ----------------
// Level 1: bin edges by dst>>10 (98 buckets of 1024 nodes). Per-block LDS histogram,
// block-reserved contiguous runs -> append writes are ~256B chunks (full lines).
// Level 2: deg-count and CSR-fill stream the BUCKET-SORTED pairs, so all writes/
// atomics touching one adj cache line occur within a ~16K-pair window -> L2-resident,
// compulsory-only writebacks (fixes the 10x write amplification of the full-sweep scatter).

__global__ __launch_bounds__(256) void bin_count_kernel(const int* __restrict__ dst,
                                                        int* __restrict__ blkhist) {
    __shared__ int hist[NBKT];
    int t = threadIdx.x, b = blockIdx.x;
    for (int i = t; i < NBKT; i += 256) hist[i] = 0;
    __syncthreads();
    int base = b * EDGES_PER_BLOCK;
    for (int i = t; i < EDGES_PER_BLOCK; i += 256)
        atomicAdd(&hist[dst[base + i] >> 10], 1);
    __syncthreads();
    for (int i = t; i < NBKT; i += 256) blkhist[i * NBIN_BLOCKS + b] = hist[i];
}

// per-bucket exclusive scan over the 512 block counts; emits bucket totals
__global__ __launch_bounds__(512) void binscanA_kernel(int* __restrict__ blkhist,
                                                       int* __restrict__ bkt_total) {
    __shared__ int buf[NBIN_BLOCKS];
    int bucket = blockIdx.x, t = threadIdx.x;
    int v = blkhist[bucket * NBIN_BLOCKS + t];
    buf[t] = v;
    __syncthreads();
    for (int off = 1; off < NBIN_BLOCKS; off <<= 1) {
        int tv = (t >= off) ? buf[t - off] : 0;
        __syncthreads();
        buf[t] += tv;
        __syncthreads();
    }
    blkhist[bucket * NBIN_BLOCKS + t] = buf[t] - v;   // exclusive within bucket
    if (t == NBIN_BLOCKS - 1) bkt_total[bucket] = buf[t];
}

// exclusive scan of the 98 bucket totals
__global__ __launch_bounds__(128) void binscanB_kernel(const int* __restrict__ bkt_total,
                                                       int* __restrict__ bktbase) {
    __shared__ int buf[128];
    int t = threadIdx.x;
    int v = (t < NBKT) ? bkt_total[t] : 0;
    buf[t] = v;
    __syncthreads();
    for (int off = 1; off < 128; off <<= 1) {
        int tv = (t >= off) ? buf[t - off] : 0;
        __syncthreads();
        buf[t] += tv;
        __syncthreads();
    }
    if (t < NBKT) bktbase[t] = buf[t] - v;
}

__global__ __launch_bounds__(256) void bin_scatter_kernel(const int* __restrict__ src,
                                                          const int* __restrict__ dst,
                                                          const int* __restrict__ blkhist,
                                                          const int* __restrict__ bktbase,
                                                          u64* __restrict__ pairs) {
    __shared__ int lofs[NBKT];
    int t = threadIdx.x, b = blockIdx.x;
    for (int i = t; i < NBKT; i += 256)
        lofs[i] = bktbase[i] + blkhist[i * NBIN_BLOCKS + b];
    __syncthreads();
    int base = b * EDGES_PER_BLOCK;
    for (int i = t; i < EDGES_PER_BLOCK; i += 256) {
        int d = dst[base + i];
        int s = src[base + i];
        int p = atomicAdd(&lofs[d >> 10], 1);
        pairs[p] = ((u64)(u32)d << 32) | (u32)s;
    }
}

// deg count over bucket-sorted pairs: atomics hit a ~4KB deg window per active block
__global__ __launch_bounds__(256) void deg_count_kernel(const u64* __restrict__ pairs,
                                                        int* __restrict__ deg) {
    int i = blockIdx.x * 256 + threadIdx.x;
    int d = (int)(pairs[i] >> 32);
    atomicAdd(&deg[d], 1);
}

// CSR fill over bucket-sorted pairs: cursor/adj windows L2-resident
__global__ __launch_bounds__(256) void fill_pairs_kernel(const u64* __restrict__ pairs,
                                                         int* __restrict__ cursor,
                                                         int* __restrict__ adj) {
    int i = blockIdx.x * 256 + threadIdx.x;
    u64 pr = pairs[i];
    int d = (int)(pr >> 32);
    int s = (int)(pr & 0xFFFFFFFFu);
    int pos = atomicAdd(&cursor[d], 1);
    adj[pos] = s;
}

__global__ __launch_bounds__(SCAN_BLOCK) void scan1_kernel(const int* __restrict__ deg,
                                                           int* __restrict__ incl,
                                                           int* __restrict__ bsum) {
    __shared__ int buf[SCAN_BLOCK];
    int t = threadIdx.x;
    int i = blockIdx.x * SCAN_BLOCK + t;
    int v = (i < N_NODES) ? deg[i] : 0;
    buf[t] = v;
    __syncthreads();
    for (int off = 1; off < SCAN_BLOCK; off <<= 1) {
        int tv = (t >= off) ? buf[t - off] : 0;
        __syncthreads();
        buf[t] += tv;
        __syncthreads();
    }
    if (i < N_NODES) incl[i] = buf[t];
    if (t == SCAN_BLOCK - 1) bsum[blockIdx.x] = buf[t];
}

__global__ __launch_bounds__(128) void scan2_kernel(const int* __restrict__ bsum,
                                                    int* __restrict__ bpre) {
    __shared__ int buf[128];
    int t = threadIdx.x;
    int v = (t < SCAN_NBLK) ? bsum[t] : 0;
    buf[t] = v;
    __syncthreads();
    for (int off = 1; off < 128; off <<= 1) {
        int tv = (t >= off) ? buf[t - off] : 0;
        __syncthreads();
        buf[t] += tv;
        __syncthreads();
    }
    if (t < SCAN_NBLK) bpre[t] = buf[t] - v;
    if (t == 127) bpre[SCAN_NBLK] = buf[127];
}

__global__ __launch_bounds__(SCAN_BLOCK) void scan3_kernel(const int* __restrict__ incl,
                                                           const int* __restrict__ deg,
                                                           const int* __restrict__ bpre,
                                                           int* __restrict__ offsets) {
    int i = blockIdx.x * SCAN_BLOCK + threadIdx.x;
    if (i < N_NODES) offsets[i] = bpre[blockIdx.x] + incl[i] - deg[i];
    if (blockIdx.x == 0 && threadIdx.x == 0) offsets[N_NODES] = bpre[SCAN_NBLK];
}

// ---------------- aggregation: one wave per node, 8-deep unrolled gathers ----------------
__global__ __launch_bounds__(256) void agg_kernel(const u32* __restrict__ X,
                                                  const int* __restrict__ offsets,
                                                  const int* __restrict__ adj,
                                                  u32* __restrict__ out) {
    int node = blockIdx.x * 4 + (threadIdx.x >> 6);
    int l = threadIdx.x & 63;                    // lane handles 2 features (u32)
    const u32* Xl = X + l;
    u32 v = Xl[(size_t)node << 6];
    float s0 = bflo(v), s1 = bfhi(v);
    float t0 = 0.f, t1 = 0.f;
    int k = offsets[node], e = offsets[node + 1];
    for (; k + 8 <= e; k += 8) {
        int a0 = adj[k + 0], a1 = adj[k + 1], a2 = adj[k + 2], a3 = adj[k + 3];
        int a4 = adj[k + 4], a5 = adj[k + 5], a6 = adj[k + 6], a7 = adj[k + 7];
        u32 u0 = Xl[(size_t)a0 << 6];
        u32 u1 = Xl[(size_t)a1 << 6];
        u32 u2 = Xl[(size_t)a2 << 6];
        u32 u3 = Xl[(size_t)a3 << 6];
        u32 u4 = Xl[(size_t)a4 << 6];
        u32 u5 = Xl[(size_t)a5 << 6];
        u32 u6 = Xl[(size_t)a6 << 6];
        u32 u7 = Xl[(size_t)a7 << 6];
        s0 += bflo(u0); s1 += bfhi(u0);
        t0 += bflo(u1); t1 += bfhi(u1);
        s0 += bflo(u2); s1 += bfhi(u2);
        t0 += bflo(u3); t1 += bfhi(u3);
        s0 += bflo(u4); s1 += bfhi(u4);
        t0 += bflo(u5); t1 += bfhi(u5);
        s0 += bflo(u6); s1 += bfhi(u6);
        t0 += bflo(u7); t1 += bfhi(u7);
    }
    if (k + 4 <= e) {
        int a0 = adj[k + 0], a1 = adj[k + 1], a2 = adj[k + 2], a3 = adj[k + 3];
        u32 u0 = Xl[(size_t)a0 << 6];
        u32 u1 = Xl[(size_t)a1 << 6];
        u32 u2 = Xl[(size_t)a2 << 6];
        u32 u3 = Xl[(size_t)a3 << 6];
        s0 += bflo(u0); s1 += bfhi(u0);
        t0 += bflo(u1); t1 += bfhi(u1);
        s0 += bflo(u2); s1 += bfhi(u2);
        t0 += bflo(u3); t1 += bfhi(u3);
        k += 4;
    }
    for (; k < e; k++) {
        u32 u = Xl[(size_t)adj[k] << 6];
        s0 += bflo(u); s1 += bfhi(u);
    }
    out[((size_t)node << 6) + l] = (u32)f2bf(s0 + t0) | ((u32)f2bf(s1 + t1) << 16);
}

// ---------------- bf16 MFMA GEMM: out[N x 128] = A[N x 128] @ W^T + bias ----------------
// Wt: bf16 transposed [col][k]. A row-major bf16. Fuses per-block BN column stats.
template <int OUT_BF16>
__global__ __launch_bounds__(256) void gemm_mfma_kernel(const u16* __restrict__ A,
                                                        const u16* __restrict__ Wt,
                                                        const float* __restrict__ bias,
                                                        void* __restrict__ outp,
                                                        float* __restrict__ psum,
                                                        float* __restrict__ psq, int nrows) {
    __shared__ __align__(16) u16 sA[16384];  // [row][k] swizzled, 32 KB
    __shared__ __align__(16) u16 sW[16384];  // [col][k] swizzled, 32 KB

    int tid = threadIdx.x;
    int rb = blockIdx.x * 128;

    // stage W
    {
        const uint4* g = (const uint4*)Wt;
#pragma unroll
        for (int p = 0; p < 8; p++) {
            int q = p * 256 + tid;
            int r = q >> 4, seg = q & 15;
            uint4 v = g[q];
            *(uint4*)((char*)sW + r * 256 + ((seg * 16) ^ ((r & 7) << 4))) = v;
        }
    }
    // stage A tile (128 rows)
    {
#pragma unroll
        for (int p = 0; p < 8; p++) {
            int q = p * 256 + tid;
            int r = q >> 4, seg = q & 15;
            int grow = rb + r;
            uint4 v = make_uint4(0, 0, 0, 0);
            if (grow < nrows) v = *(const uint4*)(A + (size_t)grow * 128 + seg * 8);
            *(uint4*)((char*)sA + r * 256 + ((seg * 16) ^ ((r & 7) << 4))) = v;
        }
    }
    __syncthreads();

    int l = tid & 63, w = tid >> 6;
    int lr = l & 15, lg = l >> 4;

    f32x4 acc[2][8];
#pragma unroll
    for (int t = 0; t < 2; t++)
#pragma unroll
        for (int c = 0; c < 8; c++) acc[t][c] = (f32x4){0.f, 0.f, 0.f, 0.f};

#pragma unroll
    for (int kc = 0; kc < 4; kc++) {
        int kb2 = (kc * 32 + lg * 8) * 2;   // byte offset along k
        bf16x8 a[2], b[8];
#pragma unroll
        for (int t = 0; t < 2; t++) {
            int row = w * 32 + t * 16 + lr;
            a[t] = *(const bf16x8*)((const char*)sA + row * 256 + (kb2 ^ ((row & 7) << 4)));
        }
#pragma unroll
        for (int c = 0; c < 8; c++) {
            int col = c * 16 + lr;
            b[c] = *(const bf16x8*)((const char*)sW + col * 256 + (kb2 ^ ((col & 7) << 4)));
        }
#pragma unroll
        for (int t = 0; t < 2; t++)
#pragma unroll
            for (int c = 0; c < 8; c++)
                acc[t][c] = __builtin_amdgcn_mfma_f32_16x16x32_bf16(a[t], b[c], acc[t][c], 0, 0, 0);
    }

    // epilogue: bias add, store, per-lane column stats
    float bb[8];
#pragma unroll
    for (int c = 0; c < 8; c++) bb[c] = bias[c * 16 + lr];

    float sp[8], qp[8];
#pragma unroll
    for (int c = 0; c < 8; c++) { sp[c] = 0.f; qp[c] = 0.f; }

    float* outF = (float*)outp;
    u16* outB = (u16*)outp;
#pragma unroll
    for (int t = 0; t < 2; t++) {
#pragma unroll
        for (int r = 0; r < 4; r++) {
            int grow = rb + w * 32 + t * 16 + lg * 4 + r;
            bool ok = grow < nrows;
#pragma unroll
            for (int c = 0; c < 8; c++) {
                float v = acc[t][c][r] + bb[c];
                if (ok) {
                    int col = c * 16 + lr;
                    if (OUT_BF16)
                        outB[(size_t)grow * 128 + col] = f2bf(v);
                    else
                        outF[(size_t)grow * 128 + col] = v;
                    sp[c] += v;
                    qp[c] += v * v;
                }
            }
        }
    }
#pragma unroll
    for (int c = 0; c < 8; c++) {
        sp[c] += __shfl_xor(sp[c], 16); sp[c] += __shfl_xor(sp[c], 32);
        qp[c] += __shfl_xor(qp[c], 16); qp[c] += __shfl_xor(qp[c], 32);
    }
    __syncthreads();                 // sA no longer read; reuse as reduction buffer
    float* sred = (float*)sA;        // [w][c][lr][2]
    if (lg == 0) {
#pragma unroll
        for (int c = 0; c < 8; c++) {
            sred[(((w * 8 + c) * 16) + lr) * 2 + 0] = sp[c];
            sred[(((w * 8 + c) * 16) + lr) * 2 + 1] = qp[c];
        }
    }
    __syncthreads();
    if (tid < 128) {
        int c = tid >> 4, r = tid & 15;
        float s = 0.f, q = 0.f;
#pragma unroll
        for (int ww = 0; ww < 4; ww++) {
            s += sred[(((ww * 8 + c) * 16) + r) * 2 + 0];
            q += sred[(((ww * 8 + c) * 16) + r) * 2 + 1];
        }
        psum[blockIdx.x * 128 + tid] = s;
        psq[blockIdx.x * 128 + tid] = q;
    }
}

// ---------------- BN finalize (1 block, 1024 thr) ----------------
// MODE 0: scale = rsqrt(v+eps)*g ; shift = bt - m*scale
// MODE 1: r2=rsqrt(v+eps); a=r2*g; vu=v*a*a; r3=rsqrt(vu+eps); scale=a*r3*og; shift=ob-m*scale
template <int MODE>
__global__ __launch_bounds__(1024) void bnfin_kernel(const float* __restrict__ psum,
                                                     const float* __restrict__ psq,
                                                     const float* __restrict__ g,
                                                     const float* __restrict__ bt,
                                                     const float* __restrict__ og,
                                                     const float* __restrict__ ob,
                                                     float* __restrict__ scale,
                                                     float* __restrict__ shift) {
    __shared__ float ss[8][128], qq[8][128];
    int t = threadIdx.x;
    int f = t & 127, grp = t >> 7;
    float s = 0.f, q = 0.f;
    for (int b = grp; b < GEMM_BLOCKS; b += 8) {
        s += psum[b * 128 + f];
        q += psq[b * 128 + f];
    }
    ss[grp][f] = s; qq[grp][f] = q;
    __syncthreads();
    if (t < 128) {
        float S = 0.f, Q = 0.f;
#pragma unroll
        for (int i = 0; i < 8; i++) { S += ss[i][f]; Q += qq[i][f]; }
        float m = S / (float)N_NODES;
        float v = Q / (float)N_NODES - m * m;
        if (v < 0.f) v = 0.f;
        float sc, sh;
        if (MODE == 0) {
            float r = rsqrtf(v + BN_EPS);
            sc = r * g[f];
            sh = bt[f] - m * sc;
        } else {
            float r2 = rsqrtf(v + BN_EPS);
            float a = r2 * g[f];
            float vu = v * a * a;
            float r3 = rsqrtf(vu + BN_EPS);
            sc = a * r3 * og[f];
            sh = ob[f] - m * sc;
        }
        scale[f] = sc;
        shift[f] = sh;
    }
}

// ---------------- W2 fold (parallel, 128 blocks x 128 thr) ----------------
// W2ft[j][k] = bf16(sc1[k]*W2[k][j]);  b2f[j] = b2[j] + sum_k sh1[k]*W2[k][j]
__global__ __launch_bounds__(128) void foldw2_kernel(const float* __restrict__ W2,
                                                     const float* __restrict__ b2,
                                                     const float* __restrict__ sc1,
                                                     const float* __restrict__ sh1,
                                                     u16* __restrict__ W2ft,
                                                     float* __restrict__ b2f) {
    int j = blockIdx.x;
    int k = threadIdx.x;
    float w = W2[k * 128 + j];
    W2ft[j * 128 + k] = f2bf(sc1[k] * w);
    float p = sh1[k] * w;
#pragma unroll
    for (int off = 1; off < 64; off <<= 1) p += __shfl_xor(p, off);
    __shared__ float r2[2];
    if ((k & 63) == 0) r2[k >> 6] = p;
    __syncthreads();
    if (k == 0) b2f[j] = b2[j] + r2[0] + r2[1];
}

// ---------------- weight prep: all layers at once ----------------
__global__ void w1_prep_kernel(const float* __restrict__ W, u16* __restrict__ Wt) {
    int q = blockIdx.x * 256 + threadIdx.x;   // 192 blocks x 256 = 3*16384
    int layer = q >> 14;
    int r = q & 16383;
    int j = r >> 7, k = r & 127;
    Wt[q] = f2bf(W[layer * 16384 + k * 128 + j]);
}

// ---------------- relu-affine, bf16 in -> bf16 out (layers 0..L-2) ----------------
__global__ __launch_bounds__(256) void relu_affine_bf16_kernel(const u16* __restrict__ Hb,
                                                               const float* __restrict__ scale,
                                                               const float* __restrict__ shift,
                                                               u16* __restrict__ xb) {
    size_t i4 = (size_t)blockIdx.x * 256 + threadIdx.x;   // 4 bf16 / thread
    int fb = ((int)(i4 & 31)) * 4;
    uint2 hv = ((const uint2*)Hb)[i4];
    float4 sc = *(const float4*)&scale[fb];
    float4 sh = *(const float4*)&shift[fb];
    float y0 = fmaxf(bflo(hv.x) * sc.x + sh.x, 0.f);
    float y1 = fmaxf(bfhi(hv.x) * sc.y + sh.y, 0.f);
    float y2 = fmaxf(bflo(hv.y) * sc.z + sh.z, 0.f);
    float y3 = fmaxf(bfhi(hv.y) * sc.w + sh.w, 0.f);
    u32 lo = (u32)f2bf(y0) | ((u32)f2bf(y1) << 16);
    u32 hi = (u32)f2bf(y2) | ((u32)f2bf(y3) << 16);
    ((uint2*)xb)[i4] = make_uint2(lo, hi);
}

// ---------------- relu-affine, final layer: fp32 in-place ----------------
__global__ __launch_bounds__(256) void relu_affine_final_kernel(float* __restrict__ H,
                                                                const float* __restrict__ scale,
                                                                const float* __restrict__ shift) {
    size_t i4 = (size_t)blockIdx.x * 256 + threadIdx.x;
    int fb = ((int)(i4 & 31)) * 4;
    float4 h = ((const float4*)H)[i4];
    float4 sc = *(const float4*)&scale[fb];
    float4 sh = *(const float4*)&shift[fb];
    float4 y;
    y.x = fmaxf(h.x * sc.x + sh.x, 0.f);
    y.y = fmaxf(h.y * sc.y + sh.y, 0.f);
    y.z = fmaxf(h.z * sc.z + sh.z, 0.f);
    y.w = fmaxf(h.w * sc.w + sh.w, 0.f);
    ((float4*)H)[i4] = y;
}

// ---------------- readout ----------------
__global__ __launch_bounds__(128) void graph_embed_part_kernel(const float* __restrict__ X,
                                                               const float* __restrict__ w,
                                                               const int* __restrict__ batch,
                                                               float* __restrict__ gpart) {
    int g = blockIdx.x;
    int sl = blockIdx.y;
    int f = threadIdx.x;
    int lo = 0, hi = N_NODES;
    while (lo < hi) { int mid = (lo + hi) >> 1; if (batch[mid] < g) lo = mid + 1; else hi = mid; }
    int s = lo;
    lo = 0; hi = N_NODES;
    while (lo < hi) { int mid = (lo + hi) >> 1; if (batch[mid] < g + 1) lo = mid + 1; else hi = mid; }
    int e = lo;
    int cnt = e - s;
    int per = (cnt + GE_SLICES - 1) / GE_SLICES;
    int rs = s + sl * per;
    int re = rs + per; if (re > e) re = e;
    float acc = 0.f;
    for (int r = rs; r < re; r++) acc += X[(size_t)r * DF + f] * w[r];
    gpart[((size_t)g * GE_SLICES + sl) * DF + f] = acc;
}

__global__ __launch_bounds__(128) void graph_embed_reduce_kernel(const float* __restrict__ gpart,
                                                                 float* __restrict__ ge) {
    int g = blockIdx.x, f = threadIdx.x;
    float a = 0.f;
#pragma unroll
    for (int s = 0; s < GE_SLICES; s++) a += gpart[((size_t)g * GE_SLICES + s) * DF + f];
    ge[g * DF + f] = a;
}

__global__ void final_fc_kernel(const float* __restrict__ ge, const float* __restrict__ fcW,
                                const float* __restrict__ fcb, float* __restrict__ out) {
    int idx = blockIdx.x * blockDim.x + threadIdx.x;  // G*C = 256
    if (idx < NG * NC) {
        int g = idx / NC, c = idx % NC;
        float acc = fcb[c];
        for (int d = 0; d < DF; d++) acc += ge[g * DF + d] * fcW[d * NC + c];
        out[idx] = acc;
    }
}

// ---------------- launcher ----------------
extern "C" void kernel_launch(void* const* d_in, const int* in_sizes, int n_in,
                              void* d_out, int out_size, void* d_ws, size_t ws_size,
                              hipStream_t stream) {
    const float* x    = (const float*)d_in[0];
    const int*   ei   = (const int*)d_in[1];
    const int*   src  = ei;
    const int*   dst  = ei + N_EDGES;
    const float* nw   = (const float*)d_in[2];
    const int*   batch= (const int*)d_in[3];
    const float* W1   = (const float*)d_in[4];
    const float* b1   = (const float*)d_in[5];
    const float* g1   = (const float*)d_in[6];
    const float* bt1  = (const float*)d_in[7];
    const float* W2   = (const float*)d_in[8];
    const float* b2   = (const float*)d_in[9];
    const float* g2   = (const float*)d_in[10];
    const float* bt2  = (const float*)d_in[11];
    const float* og   = (const float*)d_in[12];
    const float* ob   = (const float*)d_in[13];
    const float* fcW  = (const float*)d_in[14];
    const float* fcb  = (const float*)d_in[15];

    float* out_f    = (float*)d_out;
    float* node_out = out_f;                              // N*DF fp32
    float* ge       = out_f + (size_t)N_NODES * DF;       // G*DF
    float* cls      = ge + NG * DF;                       // G*C

    char* w = (char*)d_ws;
    auto alloc = [&](size_t bytes) { char* p = w; w += (bytes + 255) & ~(size_t)255; return p; };

    u16*   XB      = (u16*)alloc((size_t)N_NODES * DF * 2);     // row-major bf16 features
    u16*   AGG     = (u16*)alloc((size_t)N_NODES * DF * 2);     // bf16 agg output / bf16 h2
    u16*   H1      = (u16*)alloc((size_t)N_NODES * DF * 2);     // bf16 h1_raw
    int*   deg     = (int*)alloc((size_t)N_NODES * 4);
    int*   cursor  = (int*)alloc((size_t)N_NODES * 4);
    int*   offsets = (int*)alloc((size_t)(N_NODES + 1) * 4);
    int*   incl    = (int*)alloc((size_t)N_NODES * 4);
    int*   bsum    = (int*)alloc((SCAN_NBLK + 1) * 4);
    int*   bpre    = (int*)alloc((SCAN_NBLK + 1) * 4);
    int*   adj     = (int*)alloc((size_t)N_EDGES * 4);
    float* psum    = (float*)alloc((size_t)GEMM_BLOCKS * 128 * 4);
    float* psq     = (float*)alloc((size_t)GEMM_BLOCKS * 128 * 4);
    u16*   W1t     = (u16*)alloc((size_t)NL * 16384 * 2);
    u16*   W2ft    = (u16*)alloc(16384 * 2);
    float* b2f     = (float*)alloc(128 * 4);
    float* sc1     = (float*)alloc(128 * 4);
    float* sh1     = (float*)alloc(128 * 4);
    float* scaleO  = (float*)alloc(128 * 4);
    float* shiftO  = (float*)alloc(128 * 4);
    float* gpart   = (float*)alloc((size_t)NG * GE_SLICES * DF * 4);
    int*   blkhist = (int*)alloc((size_t)NBKT * NBIN_BLOCKS * 4);
    int*   bkt_tot = (int*)alloc(NBKT * 4);
    int*   bktbase = (int*)alloc(NBKT * 4);

    // pairs buffer (12.8MB) aliases AGG (dead until first agg_kernel)
    u64* pairs = (u64*)AGG;

    // bf16 mirror of input x + weight transposes
    cvt_x_kernel<<<12500, 256, 0, stream>>>(x, XB);
    w1_prep_kernel<<<192, 256, 0, stream>>>(W1, W1t);

    // ---- CSR build via bucket sort ----
    hipMemsetAsync(deg, 0, (size_t)N_NODES * 4, stream);
    bin_count_kernel<<<NBIN_BLOCKS, 256, 0, stream>>>(dst, blkhist);
    binscanA_kernel<<<NBKT, NBIN_BLOCKS, 0, stream>>>(blkhist, bkt_tot);
    binscanB_kernel<<<1, 128, 0, stream>>>(bkt_tot, bktbase);
    bin_scatter_kernel<<<NBIN_BLOCKS, 256, 0, stream>>>(src, dst, blkhist, bktbase, pairs);
    deg_count_kernel<<<N_EDGES / 256, 256, 0, stream>>>(pairs, deg);
    scan1_kernel<<<SCAN_NBLK, SCAN_BLOCK, 0, stream>>>(deg, incl, bsum);
    scan2_kernel<<<1, 128, 0, stream>>>(bsum, bpre);
    scan3_kernel<<<SCAN_NBLK, SCAN_BLOCK, 0, stream>>>(incl, deg, bpre, offsets);
    hipMemcpyAsync(cursor, offsets, (size_t)N_NODES * 4, hipMemcpyDeviceToDevice, stream);
    fill_pairs_kernel<<<N_EDGES / 256, 256, 0, stream>>>(pairs, cursor, adj);

    for (int l = 0; l < NL; l++) {
        // agg = X + sum_{in-edges} X[src]   (bf16 row-major, MLP-unrolled)
        agg_kernel<<<N_NODES / 4, 256, 0, stream>>>((const u32*)XB, offsets, adj, (u32*)AGG);
        // h1_raw = agg @ W1 + b1 (bf16 out) + fused BN1 stats
        gemm_mfma_kernel<1><<<GEMM_BLOCKS, 256, 0, stream>>>(AGG, W1t + (size_t)l * 16384,
                                                             b1 + l * DF, H1, psum, psq, N_NODES);
        // BN1 finalize, then parallel fold into W2
        bnfin_kernel<0><<<1, 1024, 0, stream>>>(psum, psq, g1 + l * DF, bt1 + l * DF,
                                                nullptr, nullptr, sc1, sh1);
        foldw2_kernel<<<128, 128, 0, stream>>>(W2 + (size_t)l * DF * DF, b2 + l * DF,
                                               sc1, sh1, W2ft, b2f);
        // h2_raw = h1_raw @ W2f + b2f (+ fused stats); bf16 for l<2, fp32 for final
        if (l < NL - 1) {
            gemm_mfma_kernel<1><<<GEMM_BLOCKS, 256, 0, stream>>>(H1, W2ft, b2f, AGG,
                                                                 psum, psq, N_NODES);
        } else {
            gemm_mfma_kernel<0><<<GEMM_BLOCKS, 256, 0, stream>>>(H1, W2ft, b2f, node_out,
                                                                 psum, psq, N_NODES);
        }
        bnfin_kernel<1><<<1, 1024, 0, stream>>>(psum, psq, g2 + l * DF, bt2 + l * DF,
                                                og + l * DF, ob + l * DF, scaleO, shiftO);
        if (l < NL - 1) {
            relu_affine_bf16_kernel<<<12500, 256, 0, stream>>>(AGG, scaleO, shiftO, XB);
        } else {
            relu_affine_final_kernel<<<12500, 256, 0, stream>>>(node_out, scaleO, shiftO);
        }
    }

    graph_embed_part_kernel<<<dim3(NG, GE_SLICES), 128, 0, stream>>>(node_out, nw, batch, gpart);
    graph_embed_reduce_kernel<<<NG, 128, 0, stream>>>(gpart, ge);
    final_fc_kernel<<<1, 256, 0, stream>>>(ge, fcW, fcb, cls);
}

// Round 11
// 622.795 us; speedup vs baseline: 1.1913x; 1.1448x over previous
//
#include <hip/hip_runtime.h>

#define N_NODES 100000
#define N_EDGES 1600000
#define DF 128
#define NL 3
#define NG 128
#define NC 2
#define BN_EPS 1e-5f
#define GEMM_BLOCKS ((N_NODES + 127) / 128)   // 782
#define SCAN_BLOCK 1024
#define SCAN_NBLK ((N_NODES + SCAN_BLOCK - 1) / SCAN_BLOCK)  // 98
#define GE_SLICES 16

// ---- bucket sort params ----
#define NBKT 98                               // dst >> 10  -> 0..97
#define NBIN_BLOCKS 512
#define EDGES_PER_BLOCK (N_EDGES / NBIN_BLOCKS)  // 3125

typedef unsigned int u32;
typedef unsigned short u16;
typedef unsigned long long u64;

using bf16x8 = __attribute__((ext_vector_type(8))) short;
using f32x4  = __attribute__((ext_vector_type(4))) float;

__device__ __forceinline__ u16 f2bf(float f) {
    u32 u = __float_as_uint(f);
    u32 r = (u + 0x7FFFu + ((u >> 16) & 1u)) >> 16;
    return (u16)r;
}
__device__ __forceinline__ float bflo(u32 v) { return __uint_as_float(v << 16); }
__device__ __forceinline__ float bfhi(u32 v) { return __uint_as_float(v & 0xFFFF0000u); }

// ---------------- fp32 x -> row-major bf16 mirror ----------------
__global__ __launch_bounds__(256) void cvt_x_kernel(const float* __restrict__ x,
                                                    u16* __restrict__ xb) {
    size_t i4 = (size_t)blockIdx.x * 256 + threadIdx.x;   // one float4 / thread
    float4 v = ((const float4*)x)[i4];
    u32 lo = (u32)f2bf(v.x) | ((u32)f2bf(v.y) << 16);
    u32 hi = (u32)f2bf(v.z) | ((u32)f2bf(v.w) << 16);
    ((uint2*)xb)[i4] = make_uint2(lo, hi);
}

// ---------------- CSR build via 2-level bucket sort ----------------
__global__ __launch_bounds__(256) void bin_count_kernel(const int* __restrict__ dst,
                                                        int* __restrict__ blkhist) {
    __shared__ int hist[NBKT];
    int t = threadIdx.x, b = blockIdx.x;
    for (int i = t; i < NBKT; i += 256) hist[i] = 0;
    __syncthreads();
    int base = b * EDGES_PER_BLOCK;
    for (int i = t; i < EDGES_PER_BLOCK; i += 256)
        atomicAdd(&hist[dst[base + i] >> 10], 1);
    __syncthreads();
    for (int i = t; i < NBKT; i += 256) blkhist[i * NBIN_BLOCKS + b] = hist[i];
}

__global__ __launch_bounds__(512) void binscanA_kernel(int* __restrict__ blkhist,
                                                       int* __restrict__ bkt_total) {
    __shared__ int buf[NBIN_BLOCKS];
    int bucket = blockIdx.x, t = threadIdx.x;
    int v = blkhist[bucket * NBIN_BLOCKS + t];
    buf[t] = v;
    __syncthreads();
    for (int off = 1; off < NBIN_BLOCKS; off <<= 1) {
        int tv = (t >= off) ? buf[t - off] : 0;
        __syncthreads();
        buf[t] += tv;
        __syncthreads();
    }
    blkhist[bucket * NBIN_BLOCKS + t] = buf[t] - v;   // exclusive within bucket
    if (t == NBIN_BLOCKS - 1) bkt_total[bucket] = buf[t];
}

__global__ __launch_bounds__(128) void binscanB_kernel(const int* __restrict__ bkt_total,
                                                       int* __restrict__ bktbase) {
    __shared__ int buf[128];
    int t = threadIdx.x;
    int v = (t < NBKT) ? bkt_total[t] : 0;
    buf[t] = v;
    __syncthreads();
    for (int off = 1; off < 128; off <<= 1) {
        int tv = (t >= off) ? buf[t - off] : 0;
        __syncthreads();
        buf[t] += tv;
        __syncthreads();
    }
    if (t < NBKT) bktbase[t] = buf[t] - v;
}

__global__ __launch_bounds__(256) void bin_scatter_kernel(const int* __restrict__ src,
                                                          const int* __restrict__ dst,
                                                          const int* __restrict__ blkhist,
                                                          const int* __restrict__ bktbase,
                                                          u64* __restrict__ pairs) {
    __shared__ int lofs[NBKT];
    int t = threadIdx.x, b = blockIdx.x;
    for (int i = t; i < NBKT; i += 256)
        lofs[i] = bktbase[i] + blkhist[i * NBIN_BLOCKS + b];
    __syncthreads();
    int base = b * EDGES_PER_BLOCK;
    for (int i = t; i < EDGES_PER_BLOCK; i += 256) {
        int d = dst[base + i];
        int s = src[base + i];
        int p = atomicAdd(&lofs[d >> 10], 1);
        pairs[p] = ((u64)(u32)d << 32) | (u32)s;
    }
}

__global__ __launch_bounds__(256) void deg_count_kernel(const u64* __restrict__ pairs,
                                                        int* __restrict__ deg) {
    int i = blockIdx.x * 256 + threadIdx.x;
    int d = (int)(pairs[i] >> 32);
    atomicAdd(&deg[d], 1);
}

__global__ __launch_bounds__(256) void fill_pairs_kernel(const u64* __restrict__ pairs,
                                                         int* __restrict__ cursor,
                                                         int* __restrict__ adj) {
    int i = blockIdx.x * 256 + threadIdx.x;
    u64 pr = pairs[i];
    int d = (int)(pr >> 32);
    int s = (int)(pr & 0xFFFFFFFFu);
    int pos = atomicAdd(&cursor[d], 1);
    adj[pos] = s;
}

__global__ __launch_bounds__(SCAN_BLOCK) void scan1_kernel(const int* __restrict__ deg,
                                                           int* __restrict__ incl,
                                                           int* __restrict__ bsum) {
    __shared__ int buf[SCAN_BLOCK];
    int t = threadIdx.x;
    int i = blockIdx.x * SCAN_BLOCK + t;
    int v = (i < N_NODES) ? deg[i] : 0;
    buf[t] = v;
    __syncthreads();
    for (int off = 1; off < SCAN_BLOCK; off <<= 1) {
        int tv = (t >= off) ? buf[t - off] : 0;
        __syncthreads();
        buf[t] += tv;
        __syncthreads();
    }
    if (i < N_NODES) incl[i] = buf[t];
    if (t == SCAN_BLOCK - 1) bsum[blockIdx.x] = buf[t];
}

__global__ __launch_bounds__(128) void scan2_kernel(const int* __restrict__ bsum,
                                                    int* __restrict__ bpre) {
    __shared__ int buf[128];
    int t = threadIdx.x;
    int v = (t < SCAN_NBLK) ? bsum[t] : 0;
    buf[t] = v;
    __syncthreads();
    for (int off = 1; off < 128; off <<= 1) {
        int tv = (t >= off) ? buf[t - off] : 0;
        __syncthreads();
        buf[t] += tv;
        __syncthreads();
    }
    if (t < SCAN_NBLK) bpre[t] = buf[t] - v;
    if (t == 127) bpre[SCAN_NBLK] = buf[127];
}

__global__ __launch_bounds__(SCAN_BLOCK) void scan3_kernel(const int* __restrict__ incl,
                                                           const int* __restrict__ deg,
                                                           const int* __restrict__ bpre,
                                                           int* __restrict__ offsets) {
    int i = blockIdx.x * SCAN_BLOCK + threadIdx.x;
    if (i < N_NODES) offsets[i] = bpre[blockIdx.x] + incl[i] - deg[i];
    if (blockIdx.x == 0 && threadIdx.x == 0) offsets[N_NODES] = bpre[SCAN_NBLK];
}

// ---------------- aggregation: one wave per node, 8-deep unrolled gathers ----------------
__global__ __launch_bounds__(256) void agg_kernel(const u32* __restrict__ X,
                                                  const int* __restrict__ offsets,
                                                  const int* __restrict__ adj,
                                                  u32* __restrict__ out) {
    int node = blockIdx.x * 4 + (threadIdx.x >> 6);
    int l = threadIdx.x & 63;                    // lane handles 2 features (u32)
    const u32* Xl = X + l;
    u32 v = Xl[(size_t)node << 6];
    float s0 = bflo(v), s1 = bfhi(v);
    float t0 = 0.f, t1 = 0.f;
    int k = offsets[node], e = offsets[node + 1];
    for (; k + 8 <= e; k += 8) {
        int a0 = adj[k + 0], a1 = adj[k + 1], a2 = adj[k + 2], a3 = adj[k + 3];
        int a4 = adj[k + 4], a5 = adj[k + 5], a6 = adj[k + 6], a7 = adj[k + 7];
        u32 u0 = Xl[(size_t)a0 << 6];
        u32 u1 = Xl[(size_t)a1 << 6];
        u32 u2 = Xl[(size_t)a2 << 6];
        u32 u3 = Xl[(size_t)a3 << 6];
        u32 u4 = Xl[(size_t)a4 << 6];
        u32 u5 = Xl[(size_t)a5 << 6];
        u32 u6 = Xl[(size_t)a6 << 6];
        u32 u7 = Xl[(size_t)a7 << 6];
        s0 += bflo(u0); s1 += bfhi(u0);
        t0 += bflo(u1); t1 += bfhi(u1);
        s0 += bflo(u2); s1 += bfhi(u2);
        t0 += bflo(u3); t1 += bfhi(u3);
        s0 += bflo(u4); s1 += bfhi(u4);
        t0 += bflo(u5); t1 += bfhi(u5);
        s0 += bflo(u6); s1 += bfhi(u6);
        t0 += bflo(u7); t1 += bfhi(u7);
    }
    if (k + 4 <= e) {
        int a0 = adj[k + 0], a1 = adj[k + 1], a2 = adj[k + 2], a3 = adj[k + 3];
        u32 u0 = Xl[(size_t)a0 << 6];
        u32 u1 = Xl[(size_t)a1 << 6];
        u32 u2 = Xl[(size_t)a2 << 6];
        u32 u3 = Xl[(size_t)a3 << 6];
        s0 += bflo(u0); s1 += bfhi(u0);
        t0 += bflo(u1); t1 += bfhi(u1);
        s0 += bflo(u2); s1 += bfhi(u2);
        t0 += bflo(u3); t1 += bfhi(u3);
        k += 4;
    }
    for (; k < e; k++) {
        u32 u = Xl[(size_t)adj[k] << 6];
        s0 += bflo(u); s1 += bfhi(u);
    }
    out[((size_t)node << 6) + l] = (u32)f2bf(s0 + t0) | ((u32)f2bf(s1 + t1) << 16);
}

// ---------------- bf16 MFMA GEMM: out[N x 128] = A[N x 128] @ W^T + bias ----------------
// Wt: bf16 transposed [col][k] in swizzled LDS. A fragments loaded DIRECTLY from global
// (each 16B fragment read exactly once per block; 4 lanes share a 64B line -> coalesced).
// Column stats (sum, sumsq) accumulated via one atomicAdd per feature per block.
template <int OUT_BF16>
__global__ __launch_bounds__(256) void gemm_mfma_kernel(const u16* __restrict__ A,
                                                        const u16* __restrict__ Wt,
                                                        const float* __restrict__ bias,
                                                        void* __restrict__ outp,
                                                        float* __restrict__ psum,
                                                        float* __restrict__ psq, int nrows) {
    __shared__ __align__(16) u16 sW[16384];  // [col][k] swizzled, 32 KB

    int tid = threadIdx.x;
    int rb = blockIdx.x * 128;

    // stage W (swizzled)
    {
        const uint4* g = (const uint4*)Wt;
#pragma unroll
        for (int p = 0; p < 8; p++) {
            int q = p * 256 + tid;
            int r = q >> 4, seg = q & 15;
            uint4 v = g[q];
            *(uint4*)((char*)sW + r * 256 + ((seg * 16) ^ ((r & 7) << 4))) = v;
        }
    }

    int l = tid & 63, w = tid >> 6;
    int lr = l & 15, lg = l >> 4;

    // preload all A fragments (8 x dwordx4 in flight)
    bf16x8 afr[2][4];
#pragma unroll
    for (int t = 0; t < 2; t++) {
        int grow = rb + w * 32 + t * 16 + lr;
        bool ok = grow < nrows;
#pragma unroll
        for (int kc = 0; kc < 4; kc++) {
            bf16x8 z = {0, 0, 0, 0, 0, 0, 0, 0};
            if (ok) z = *(const bf16x8*)(A + (size_t)grow * 128 + kc * 32 + lg * 8);
            afr[t][kc] = z;
        }
    }
    __syncthreads();

    f32x4 acc[2][8];
#pragma unroll
    for (int t = 0; t < 2; t++)
#pragma unroll
        for (int c = 0; c < 8; c++) acc[t][c] = (f32x4){0.f, 0.f, 0.f, 0.f};

#pragma unroll
    for (int kc = 0; kc < 4; kc++) {
        int kb2 = (kc * 32 + lg * 8) * 2;   // byte offset along k
        bf16x8 b[8];
#pragma unroll
        for (int c = 0; c < 8; c++) {
            int col = c * 16 + lr;
            b[c] = *(const bf16x8*)((const char*)sW + col * 256 + (kb2 ^ ((col & 7) << 4)));
        }
#pragma unroll
        for (int t = 0; t < 2; t++)
#pragma unroll
            for (int c = 0; c < 8; c++)
                acc[t][c] = __builtin_amdgcn_mfma_f32_16x16x32_bf16(afr[t][kc], b[c], acc[t][c], 0, 0, 0);
    }

    // epilogue: bias add, store, per-lane column stats
    float bb[8];
#pragma unroll
    for (int c = 0; c < 8; c++) bb[c] = bias[c * 16 + lr];

    float sp[8], qp[8];
#pragma unroll
    for (int c = 0; c < 8; c++) { sp[c] = 0.f; qp[c] = 0.f; }

    float* outF = (float*)outp;
    u16* outB = (u16*)outp;
#pragma unroll
    for (int t = 0; t < 2; t++) {
#pragma unroll
        for (int r = 0; r < 4; r++) {
            int grow = rb + w * 32 + t * 16 + lg * 4 + r;
            bool ok = grow < nrows;
#pragma unroll
            for (int c = 0; c < 8; c++) {
                float v = acc[t][c][r] + bb[c];
                if (ok) {
                    int col = c * 16 + lr;
                    if (OUT_BF16)
                        outB[(size_t)grow * 128 + col] = f2bf(v);
                    else
                        outF[(size_t)grow * 128 + col] = v;
                    sp[c] += v;
                    qp[c] += v * v;
                }
            }
        }
    }
#pragma unroll
    for (int c = 0; c < 8; c++) {
        sp[c] += __shfl_xor(sp[c], 16); sp[c] += __shfl_xor(sp[c], 32);
        qp[c] += __shfl_xor(qp[c], 16); qp[c] += __shfl_xor(qp[c], 32);
    }
    __syncthreads();                 // sW no longer read; reuse as reduction buffer
    float* sred = (float*)sW;        // [w][c][lr][2] = 1024 floats
    if (lg == 0) {
#pragma unroll
        for (int c = 0; c < 8; c++) {
            sred[(((w * 8 + c) * 16) + lr) * 2 + 0] = sp[c];
            sred[(((w * 8 + c) * 16) + lr) * 2 + 1] = qp[c];
        }
    }
    __syncthreads();
    if (tid < 128) {
        int c = tid >> 4, r = tid & 15;
        float s = 0.f, q = 0.f;
#pragma unroll
        for (int ww = 0; ww < 4; ww++) {
            s += sred[(((ww * 8 + c) * 16) + r) * 2 + 0];
            q += sred[(((ww * 8 + c) * 16) + r) * 2 + 1];
        }
        atomicAdd(&psum[tid], s);
        atomicAdd(&psq[tid], q);
    }
}

// ---------------- BN1 finalize fused into W2 fold (128 blocks x 128 thr) ----------------
// Each block recomputes sc1/sh1 from the 256 atomic-accumulated stat floats (trivial),
// then folds its output column j: W2ft[j][k] = bf16(sc1[k]*W2[k][j]);
// b2f[j] = b2[j] + sum_k sh1[k]*W2[k][j]
__global__ __launch_bounds__(128) void bnfold_kernel(const float* __restrict__ psum,
                                                     const float* __restrict__ psq,
                                                     const float* __restrict__ g,
                                                     const float* __restrict__ bt,
                                                     const float* __restrict__ W2,
                                                     const float* __restrict__ b2,
                                                     u16* __restrict__ W2ft,
                                                     float* __restrict__ b2f) {
    __shared__ float sc1[128], sh1[128];
    int k = threadIdx.x;
    int j = blockIdx.x;
    {
        float S = psum[k], Q = psq[k];
        float m = S / (float)N_NODES;
        float v = Q / (float)N_NODES - m * m;
        if (v < 0.f) v = 0.f;
        float r = rsqrtf(v + BN_EPS);
        float sc = r * g[k];
        sc1[k] = sc;
        sh1[k] = bt[k] - m * sc;
    }
    __syncthreads();
    float w = W2[k * 128 + j];
    W2ft[j * 128 + k] = f2bf(sc1[k] * w);
    float p = sh1[k] * w;
#pragma unroll
    for (int off = 1; off < 64; off <<= 1) p += __shfl_xor(p, off);
    __shared__ float r2[2];
    if ((k & 63) == 0) r2[k >> 6] = p;
    __syncthreads();
    if (k == 0) b2f[j] = b2[j] + r2[0] + r2[1];
}

// ---------------- BN2 + outer BN finalize (tiny: 1 block, 128 thr) ----------------
__global__ __launch_bounds__(128) void bnfin2_kernel(const float* __restrict__ psum,
                                                     const float* __restrict__ psq,
                                                     const float* __restrict__ g,
                                                     const float* __restrict__ bt,
                                                     const float* __restrict__ og,
                                                     const float* __restrict__ ob,
                                                     float* __restrict__ scale,
                                                     float* __restrict__ shift) {
    int f = threadIdx.x;
    float S = psum[f], Q = psq[f];
    float m = S / (float)N_NODES;
    float v = Q / (float)N_NODES - m * m;
    if (v < 0.f) v = 0.f;
    float r2 = rsqrtf(v + BN_EPS);
    float a = r2 * g[f];
    float vu = v * a * a;
    float r3 = rsqrtf(vu + BN_EPS);
    float sc = a * r3 * og[f];
    scale[f] = sc;
    shift[f] = ob[f] - m * sc;
}

// ---------------- weight prep: all layers at once ----------------
__global__ void w1_prep_kernel(const float* __restrict__ W, u16* __restrict__ Wt) {
    int q = blockIdx.x * 256 + threadIdx.x;   // 192 blocks x 256 = 3*16384
    int layer = q >> 14;
    int r = q & 16383;
    int j = r >> 7, k = r & 127;
    Wt[q] = f2bf(W[layer * 16384 + k * 128 + j]);
}

// ---------------- relu-affine, bf16 in -> bf16 out (layers 0..L-2) ----------------
__global__ __launch_bounds__(256) void relu_affine_bf16_kernel(const u16* __restrict__ Hb,
                                                               const float* __restrict__ scale,
                                                               const float* __restrict__ shift,
                                                               u16* __restrict__ xb) {
    size_t i4 = (size_t)blockIdx.x * 256 + threadIdx.x;   // 4 bf16 / thread
    int fb = ((int)(i4 & 31)) * 4;
    uint2 hv = ((const uint2*)Hb)[i4];
    float4 sc = *(const float4*)&scale[fb];
    float4 sh = *(const float4*)&shift[fb];
    float y0 = fmaxf(bflo(hv.x) * sc.x + sh.x, 0.f);
    float y1 = fmaxf(bfhi(hv.x) * sc.y + sh.y, 0.f);
    float y2 = fmaxf(bflo(hv.y) * sc.z + sh.z, 0.f);
    float y3 = fmaxf(bfhi(hv.y) * sc.w + sh.w, 0.f);
    u32 lo = (u32)f2bf(y0) | ((u32)f2bf(y1) << 16);
    u32 hi = (u32)f2bf(y2) | ((u32)f2bf(y3) << 16);
    ((uint2*)xb)[i4] = make_uint2(lo, hi);
}

// ---------------- relu-affine, final layer: fp32 in-place ----------------
__global__ __launch_bounds__(256) void relu_affine_final_kernel(float* __restrict__ H,
                                                                const float* __restrict__ scale,
                                                                const float* __restrict__ shift) {
    size_t i4 = (size_t)blockIdx.x * 256 + threadIdx.x;
    int fb = ((int)(i4 & 31)) * 4;
    float4 h = ((const float4*)H)[i4];
    float4 sc = *(const float4*)&scale[fb];
    float4 sh = *(const float4*)&shift[fb];
    float4 y;
    y.x = fmaxf(h.x * sc.x + sh.x, 0.f);
    y.y = fmaxf(h.y * sc.y + sh.y, 0.f);
    y.z = fmaxf(h.z * sc.z + sh.z, 0.f);
    y.w = fmaxf(h.w * sc.w + sh.w, 0.f);
    ((float4*)H)[i4] = y;
}

// ---------------- readout ----------------
__global__ __launch_bounds__(128) void graph_embed_part_kernel(const float* __restrict__ X,
                                                               const float* __restrict__ w,
                                                               const int* __restrict__ batch,
                                                               float* __restrict__ gpart) {
    int g = blockIdx.x;
    int sl = blockIdx.y;
    int f = threadIdx.x;
    int lo = 0, hi = N_NODES;
    while (lo < hi) { int mid = (lo + hi) >> 1; if (batch[mid] < g) lo = mid + 1; else hi = mid; }
    int s = lo;
    lo = 0; hi = N_NODES;
    while (lo < hi) { int mid = (lo + hi) >> 1; if (batch[mid] < g + 1) lo = mid + 1; else hi = mid; }
    int e = lo;
    int cnt = e - s;
    int per = (cnt + GE_SLICES - 1) / GE_SLICES;
    int rs = s + sl * per;
    int re = rs + per; if (re > e) re = e;
    float acc = 0.f;
    for (int r = rs; r < re; r++) acc += X[(size_t)r * DF + f] * w[r];
    gpart[((size_t)g * GE_SLICES + sl) * DF + f] = acc;
}

__global__ __launch_bounds__(128) void graph_embed_reduce_kernel(const float* __restrict__ gpart,
                                                                 float* __restrict__ ge) {
    int g = blockIdx.x, f = threadIdx.x;
    float a = 0.f;
#pragma unroll
    for (int s = 0; s < GE_SLICES; s++) a += gpart[((size_t)g * GE_SLICES + s) * DF + f];
    ge[g * DF + f] = a;
}

__global__ void final_fc_kernel(const float* __restrict__ ge, const float* __restrict__ fcW,
                                const float* __restrict__ fcb, float* __restrict__ out) {
    int idx = blockIdx.x * blockDim.x + threadIdx.x;  // G*C = 256
    if (idx < NG * NC) {
        int g = idx / NC, c = idx % NC;
        float acc = fcb[c];
        for (int d = 0; d < DF; d++) acc += ge[g * DF + d] * fcW[d * NC + c];
        out[idx] = acc;
    }
}

// ---------------- launcher ----------------
extern "C" void kernel_launch(void* const* d_in, const int* in_sizes, int n_in,
                              void* d_out, int out_size, void* d_ws, size_t ws_size,
                              hipStream_t stream) {
    const float* x    = (const float*)d_in[0];
    const int*   ei   = (const int*)d_in[1];
    const int*   src  = ei;
    const int*   dst  = ei + N_EDGES;
    const float* nw   = (const float*)d_in[2];
    const int*   batch= (const int*)d_in[3];
    const float* W1   = (const float*)d_in[4];
    const float* b1   = (const float*)d_in[5];
    const float* g1   = (const float*)d_in[6];
    const float* bt1  = (const float*)d_in[7];
    const float* W2   = (const float*)d_in[8];
    const float* b2   = (const float*)d_in[9];
    const float* g2   = (const float*)d_in[10];
    const float* bt2  = (const float*)d_in[11];
    const float* og   = (const float*)d_in[12];
    const float* ob   = (const float*)d_in[13];
    const float* fcW  = (const float*)d_in[14];
    const float* fcb  = (const float*)d_in[15];

    float* out_f    = (float*)d_out;
    float* node_out = out_f;                              // N*DF fp32
    float* ge       = out_f + (size_t)N_NODES * DF;       // G*DF
    float* cls      = ge + NG * DF;                       // G*C

    char* w = (char*)d_ws;
    auto alloc = [&](size_t bytes) { char* p = w; w += (bytes + 255) & ~(size_t)255; return p; };

    u16*   XB      = (u16*)alloc((size_t)N_NODES * DF * 2);     // row-major bf16 features
    u16*   AGG     = (u16*)alloc((size_t)N_NODES * DF * 2);     // bf16 agg output / bf16 h2
    u16*   H1      = (u16*)alloc((size_t)N_NODES * DF * 2);     // bf16 h1_raw
    int*   deg     = (int*)alloc((size_t)N_NODES * 4);
    int*   cursor  = (int*)alloc((size_t)N_NODES * 4);
    int*   offsets = (int*)alloc((size_t)(N_NODES + 1) * 4);
    int*   incl    = (int*)alloc((size_t)N_NODES * 4);
    int*   bsum    = (int*)alloc((SCAN_NBLK + 1) * 4);
    int*   bpre    = (int*)alloc((SCAN_NBLK + 1) * 4);
    int*   adj     = (int*)alloc((size_t)N_EDGES * 4);
    float* stats   = (float*)alloc((size_t)NL * 4 * 128 * 4);   // [l][{ps1,pq1,ps2,pq2}][128]
    u16*   W1t     = (u16*)alloc((size_t)NL * 16384 * 2);
    u16*   W2ft    = (u16*)alloc(16384 * 2);
    float* b2f     = (float*)alloc(128 * 4);
    float* scaleO  = (float*)alloc(128 * 4);
    float* shiftO  = (float*)alloc(128 * 4);
    float* gpart   = (float*)alloc((size_t)NG * GE_SLICES * DF * 4);
    int*   blkhist = (int*)alloc((size_t)NBKT * NBIN_BLOCKS * 4);
    int*   bkt_tot = (int*)alloc(NBKT * 4);
    int*   bktbase = (int*)alloc(NBKT * 4);

    // pairs buffer (12.8MB) aliases AGG (dead until first agg_kernel)
    u64* pairs = (u64*)AGG;

    // bf16 mirror of input x + weight transposes + zero atomic stat buffers
    cvt_x_kernel<<<12500, 256, 0, stream>>>(x, XB);
    w1_prep_kernel<<<192, 256, 0, stream>>>(W1, W1t);
    hipMemsetAsync(stats, 0, (size_t)NL * 4 * 128 * 4, stream);

    // ---- CSR build via bucket sort ----
    hipMemsetAsync(deg, 0, (size_t)N_NODES * 4, stream);
    bin_count_kernel<<<NBIN_BLOCKS, 256, 0, stream>>>(dst, blkhist);
    binscanA_kernel<<<NBKT, NBIN_BLOCKS, 0, stream>>>(blkhist, bkt_tot);
    binscanB_kernel<<<1, 128, 0, stream>>>(bkt_tot, bktbase);
    bin_scatter_kernel<<<NBIN_BLOCKS, 256, 0, stream>>>(src, dst, blkhist, bktbase, pairs);
    deg_count_kernel<<<N_EDGES / 256, 256, 0, stream>>>(pairs, deg);
    scan1_kernel<<<SCAN_NBLK, SCAN_BLOCK, 0, stream>>>(deg, incl, bsum);
    scan2_kernel<<<1, 128, 0, stream>>>(bsum, bpre);
    scan3_kernel<<<SCAN_NBLK, SCAN_BLOCK, 0, stream>>>(incl, deg, bpre, offsets);
    hipMemcpyAsync(cursor, offsets, (size_t)N_NODES * 4, hipMemcpyDeviceToDevice, stream);
    fill_pairs_kernel<<<N_EDGES / 256, 256, 0, stream>>>(pairs, cursor, adj);

    for (int l = 0; l < NL; l++) {
        float* ps1 = stats + (size_t)l * 512;
        float* pq1 = ps1 + 128;
        float* ps2 = ps1 + 256;
        float* pq2 = ps1 + 384;
        // agg = X + sum_{in-edges} X[src]   (bf16 row-major, MLP-unrolled)
        agg_kernel<<<N_NODES / 4, 256, 0, stream>>>((const u32*)XB, offsets, adj, (u32*)AGG);
        // h1_raw = agg @ W1 + b1 (bf16 out) + atomic BN1 stats
        gemm_mfma_kernel<1><<<GEMM_BLOCKS, 256, 0, stream>>>(AGG, W1t + (size_t)l * 16384,
                                                             b1 + l * DF, H1, ps1, pq1, N_NODES);
        // BN1 finalize fused into W2 fold
        bnfold_kernel<<<128, 128, 0, stream>>>(ps1, pq1, g1 + l * DF, bt1 + l * DF,
                                               W2 + (size_t)l * DF * DF, b2 + l * DF, W2ft, b2f);
        // h2_raw = h1_raw @ W2f + b2f (+ atomic stats); bf16 for l<2, fp32 for final
        if (l < NL - 1) {
            gemm_mfma_kernel<1><<<GEMM_BLOCKS, 256, 0, stream>>>(H1, W2ft, b2f, AGG,
                                                                 ps2, pq2, N_NODES);
        } else {
            gemm_mfma_kernel<0><<<GEMM_BLOCKS, 256, 0, stream>>>(H1, W2ft, b2f, node_out,
                                                                 ps2, pq2, N_NODES);
        }
        bnfin2_kernel<<<1, 128, 0, stream>>>(ps2, pq2, g2 + l * DF, bt2 + l * DF,
                                             og + l * DF, ob + l * DF, scaleO, shiftO);
        if (l < NL - 1) {
            relu_affine_bf16_kernel<<<12500, 256, 0, stream>>>(AGG, scaleO, shiftO, XB);
        } else {
            relu_affine_final_kernel<<<12500, 256, 0, stream>>>(node_out, scaleO, shiftO);
        }
    }

    graph_embed_part_kernel<<<dim3(NG, GE_SLICES), 128, 0, stream>>>(node_out, nw, batch, gpart);
    graph_embed_reduce_kernel<<<NG, 128, 0, stream>>>(gpart, ge);
    final_fc_kernel<<<1, 256, 0, stream>>>(ge, fcW, fcb, cls);
}

// Round 12
// 467.780 us; speedup vs baseline: 1.5861x; 1.3314x over previous
//
#include <hip/hip_runtime.h>

#define N_NODES 100000
#define N_EDGES 1600000
#define DF 128
#define NL 3
#define NG 128
#define NC 2
#define BN_EPS 1e-5f
#define GEMM_BLOCKS ((N_NODES + 127) / 128)   // 782
#define GE_SLICES 16

// ---- bucket sort params ----
#define NBKT 98                               // dst >> 10  -> 0..97
#define NBIN_BLOCKS 512
#define EDGES_PER_BLOCK (N_EDGES / NBIN_BLOCKS)  // 3125

typedef unsigned int u32;
typedef unsigned short u16;
typedef unsigned long long u64;

using bf16x8 = __attribute__((ext_vector_type(8))) short;
using f32x4  = __attribute__((ext_vector_type(4))) float;

__device__ __forceinline__ u16 f2bf(float f) {
    u32 u = __float_as_uint(f);
    u32 r = (u + 0x7FFFu + ((u >> 16) & 1u)) >> 16;
    return (u16)r;
}
__device__ __forceinline__ float bflo(u32 v) { return __uint_as_float(v << 16); }
__device__ __forceinline__ float bfhi(u32 v) { return __uint_as_float(v & 0xFFFF0000u); }

// ---------------- fp32 x -> row-major bf16 mirror ----------------
__global__ __launch_bounds__(256) void cvt_x_kernel(const float* __restrict__ x,
                                                    u16* __restrict__ xb) {
    size_t i4 = (size_t)blockIdx.x * 256 + threadIdx.x;   // one float4 / thread
    float4 v = ((const float4*)x)[i4];
    u32 lo = (u32)f2bf(v.x) | ((u32)f2bf(v.y) << 16);
    u32 hi = (u32)f2bf(v.z) | ((u32)f2bf(v.w) << 16);
    ((uint2*)xb)[i4] = make_uint2(lo, hi);
}

// ---------------- CSR build via 2-level bucket sort ----------------
__global__ __launch_bounds__(256) void bin_count_kernel(const int* __restrict__ dst,
                                                        int* __restrict__ blkhist) {
    __shared__ int hist[NBKT];
    int t = threadIdx.x, b = blockIdx.x;
    for (int i = t; i < NBKT; i += 256) hist[i] = 0;
    __syncthreads();
    int base = b * EDGES_PER_BLOCK;
    for (int i = t; i < EDGES_PER_BLOCK; i += 256)
        atomicAdd(&hist[dst[base + i] >> 10], 1);
    __syncthreads();
    for (int i = t; i < NBKT; i += 256) blkhist[i * NBIN_BLOCKS + b] = hist[i];
}

__global__ __launch_bounds__(512) void binscanA_kernel(int* __restrict__ blkhist,
                                                       int* __restrict__ bkt_total) {
    __shared__ int buf[NBIN_BLOCKS];
    int bucket = blockIdx.x, t = threadIdx.x;
    int v = blkhist[bucket * NBIN_BLOCKS + t];
    buf[t] = v;
    __syncthreads();
    for (int off = 1; off < NBIN_BLOCKS; off <<= 1) {
        int tv = (t >= off) ? buf[t - off] : 0;
        __syncthreads();
        buf[t] += tv;
        __syncthreads();
    }
    blkhist[bucket * NBIN_BLOCKS + t] = buf[t] - v;   // exclusive within bucket
    if (t == NBIN_BLOCKS - 1) bkt_total[bucket] = buf[t];
}

// exclusive scan of the 98 bucket totals; also writes total at [NBKT]
__global__ __launch_bounds__(128) void binscanB_kernel(const int* __restrict__ bkt_total,
                                                       int* __restrict__ bktbase) {
    __shared__ int buf[128];
    int t = threadIdx.x;
    int v = (t < NBKT) ? bkt_total[t] : 0;
    buf[t] = v;
    __syncthreads();
    for (int off = 1; off < 128; off <<= 1) {
        int tv = (t >= off) ? buf[t - off] : 0;
        __syncthreads();
        buf[t] += tv;
        __syncthreads();
    }
    if (t < NBKT) bktbase[t] = buf[t] - v;
    if (t == NBKT - 1) bktbase[NBKT] = buf[t];
}

__global__ __launch_bounds__(256) void bin_scatter_kernel(const int* __restrict__ src,
                                                          const int* __restrict__ dst,
                                                          const int* __restrict__ blkhist,
                                                          const int* __restrict__ bktbase,
                                                          u64* __restrict__ pairs) {
    __shared__ int lofs[NBKT];
    int t = threadIdx.x, b = blockIdx.x;
    for (int i = t; i < NBKT; i += 256)
        lofs[i] = bktbase[i] + blkhist[i * NBIN_BLOCKS + b];
    __syncthreads();
    int base = b * EDGES_PER_BLOCK;
    for (int i = t; i < EDGES_PER_BLOCK; i += 256) {
        int d = dst[base + i];
        int s = src[base + i];
        int p = atomicAdd(&lofs[d >> 10], 1);
        pairs[p] = ((u64)(u32)d << 32) | (u32)s;
    }
}

// ---------------- per-bucket CSR finalize: offsets + adj in ONE kernel ----------------
// Block b owns nodes [b*1024, b*1024+1024) and the pairs slice [bktbase[b], bktbase[b+1]).
// LDS histogram -> LDS scan -> offsets; LDS cursors -> adj placement. All atomics in LDS.
__global__ __launch_bounds__(1024) void csr_build_kernel(const u64* __restrict__ pairs,
                                                         const int* __restrict__ bktbase,
                                                         int* __restrict__ offsets,
                                                         int* __restrict__ adj) {
    __shared__ int cnt[1024];
    __shared__ int buf[1024];
    int b = blockIdx.x, t = threadIdx.x;
    int nbase = b << 10;
    int pb = bktbase[b], pe = bktbase[b + 1];
    cnt[t] = 0;
    __syncthreads();
    for (int i = pb + t; i < pe; i += 1024)
        atomicAdd(&cnt[(int)(pairs[i] >> 32) - nbase], 1);
    __syncthreads();
    int v = cnt[t];
    buf[t] = v;
    __syncthreads();
    for (int off = 1; off < 1024; off <<= 1) {
        int tv = (t >= off) ? buf[t - off] : 0;
        __syncthreads();
        buf[t] += tv;
        __syncthreads();
    }
    int excl = buf[t] - v;
    int node = nbase + t;
    if (node < N_NODES) offsets[node] = pb + excl;
    if (b == NBKT - 1 && t == 0) offsets[N_NODES] = N_EDGES;
    cnt[t] = excl;          // reuse as cursor
    __syncthreads();
    for (int i = pb + t; i < pe; i += 1024) {
        u64 pr = pairs[i];
        int d = (int)(pr >> 32);
        int pos = atomicAdd(&cnt[d - nbase], 1);
        adj[pb + pos] = (int)(pr & 0xFFFFFFFFu);
    }
}

// ---------------- aggregation: one wave per node, 8-deep unrolled gathers ----------------
__global__ __launch_bounds__(256) void agg_kernel(const u32* __restrict__ X,
                                                  const int* __restrict__ offsets,
                                                  const int* __restrict__ adj,
                                                  u32* __restrict__ out) {
    int node = blockIdx.x * 4 + (threadIdx.x >> 6);
    int l = threadIdx.x & 63;                    // lane handles 2 features (u32)
    const u32* Xl = X + l;
    u32 v = Xl[(size_t)node << 6];
    float s0 = bflo(v), s1 = bfhi(v);
    float t0 = 0.f, t1 = 0.f;
    int k = offsets[node], e = offsets[node + 1];
    for (; k + 8 <= e; k += 8) {
        int a0 = adj[k + 0], a1 = adj[k + 1], a2 = adj[k + 2], a3 = adj[k + 3];
        int a4 = adj[k + 4], a5 = adj[k + 5], a6 = adj[k + 6], a7 = adj[k + 7];
        u32 u0 = Xl[(size_t)a0 << 6];
        u32 u1 = Xl[(size_t)a1 << 6];
        u32 u2 = Xl[(size_t)a2 << 6];
        u32 u3 = Xl[(size_t)a3 << 6];
        u32 u4 = Xl[(size_t)a4 << 6];
        u32 u5 = Xl[(size_t)a5 << 6];
        u32 u6 = Xl[(size_t)a6 << 6];
        u32 u7 = Xl[(size_t)a7 << 6];
        s0 += bflo(u0); s1 += bfhi(u0);
        t0 += bflo(u1); t1 += bfhi(u1);
        s0 += bflo(u2); s1 += bfhi(u2);
        t0 += bflo(u3); t1 += bfhi(u3);
        s0 += bflo(u4); s1 += bfhi(u4);
        t0 += bflo(u5); t1 += bfhi(u5);
        s0 += bflo(u6); s1 += bfhi(u6);
        t0 += bflo(u7); t1 += bfhi(u7);
    }
    if (k + 4 <= e) {
        int a0 = adj[k + 0], a1 = adj[k + 1], a2 = adj[k + 2], a3 = adj[k + 3];
        u32 u0 = Xl[(size_t)a0 << 6];
        u32 u1 = Xl[(size_t)a1 << 6];
        u32 u2 = Xl[(size_t)a2 << 6];
        u32 u3 = Xl[(size_t)a3 << 6];
        s0 += bflo(u0); s1 += bfhi(u0);
        t0 += bflo(u1); t1 += bfhi(u1);
        s0 += bflo(u2); s1 += bfhi(u2);
        t0 += bflo(u3); t1 += bfhi(u3);
        k += 4;
    }
    for (; k < e; k++) {
        u32 u = Xl[(size_t)adj[k] << 6];
        s0 += bflo(u); s1 += bfhi(u);
    }
    out[((size_t)node << 6) + l] = (u32)f2bf(s0 + t0) | ((u32)f2bf(s1 + t1) << 16);
}

// ---------------- bf16 MFMA GEMM: out[N x 128] = A[N x 128] @ W^T + bias ----------------
// Wt: bf16 transposed [col][k] in swizzled LDS. A fragments loaded DIRECTLY from global.
// Column stats written as per-block partials psumB/psqB[block][128] (coalesced, NO atomics
// -- the r11 atomic version created a 782-deep serialized RMW chain per feature address).
template <int OUT_BF16>
__global__ __launch_bounds__(256) void gemm_mfma_kernel(const u16* __restrict__ A,
                                                        const u16* __restrict__ Wt,
                                                        const float* __restrict__ bias,
                                                        void* __restrict__ outp,
                                                        float* __restrict__ psumB,
                                                        float* __restrict__ psqB, int nrows) {
    __shared__ __align__(16) u16 sW[16384];  // [col][k] swizzled, 32 KB

    int tid = threadIdx.x;
    int rb = blockIdx.x * 128;

    // stage W (swizzled)
    {
        const uint4* g = (const uint4*)Wt;
#pragma unroll
        for (int p = 0; p < 8; p++) {
            int q = p * 256 + tid;
            int r = q >> 4, seg = q & 15;
            uint4 v = g[q];
            *(uint4*)((char*)sW + r * 256 + ((seg * 16) ^ ((r & 7) << 4))) = v;
        }
    }

    int l = tid & 63, w = tid >> 6;
    int lr = l & 15, lg = l >> 4;

    // preload all A fragments (8 x dwordx4 in flight)
    bf16x8 afr[2][4];
#pragma unroll
    for (int t = 0; t < 2; t++) {
        int grow = rb + w * 32 + t * 16 + lr;
        bool ok = grow < nrows;
#pragma unroll
        for (int kc = 0; kc < 4; kc++) {
            bf16x8 z = {0, 0, 0, 0, 0, 0, 0, 0};
            if (ok) z = *(const bf16x8*)(A + (size_t)grow * 128 + kc * 32 + lg * 8);
            afr[t][kc] = z;
        }
    }
    __syncthreads();

    f32x4 acc[2][8];
#pragma unroll
    for (int t = 0; t < 2; t++)
#pragma unroll
        for (int c = 0; c < 8; c++) acc[t][c] = (f32x4){0.f, 0.f, 0.f, 0.f};

#pragma unroll
    for (int kc = 0; kc < 4; kc++) {
        int kb2 = (kc * 32 + lg * 8) * 2;   // byte offset along k
        bf16x8 b[8];
#pragma unroll
        for (int c = 0; c < 8; c++) {
            int col = c * 16 + lr;
            b[c] = *(const bf16x8*)((const char*)sW + col * 256 + (kb2 ^ ((col & 7) << 4)));
        }
#pragma unroll
        for (int t = 0; t < 2; t++)
#pragma unroll
            for (int c = 0; c < 8; c++)
                acc[t][c] = __builtin_amdgcn_mfma_f32_16x16x32_bf16(afr[t][kc], b[c], acc[t][c], 0, 0, 0);
    }

    // epilogue: bias add, store, per-lane column stats
    float bb[8];
#pragma unroll
    for (int c = 0; c < 8; c++) bb[c] = bias[c * 16 + lr];

    float sp[8], qp[8];
#pragma unroll
    for (int c = 0; c < 8; c++) { sp[c] = 0.f; qp[c] = 0.f; }

    float* outF = (float*)outp;
    u16* outB = (u16*)outp;
#pragma unroll
    for (int t = 0; t < 2; t++) {
#pragma unroll
        for (int r = 0; r < 4; r++) {
            int grow = rb + w * 32 + t * 16 + lg * 4 + r;
            bool ok = grow < nrows;
#pragma unroll
            for (int c = 0; c < 8; c++) {
                float v = acc[t][c][r] + bb[c];
                if (ok) {
                    int col = c * 16 + lr;
                    if (OUT_BF16)
                        outB[(size_t)grow * 128 + col] = f2bf(v);
                    else
                        outF[(size_t)grow * 128 + col] = v;
                    sp[c] += v;
                    qp[c] += v * v;
                }
            }
        }
    }
#pragma unroll
    for (int c = 0; c < 8; c++) {
        sp[c] += __shfl_xor(sp[c], 16); sp[c] += __shfl_xor(sp[c], 32);
        qp[c] += __shfl_xor(qp[c], 16); qp[c] += __shfl_xor(qp[c], 32);
    }
    __syncthreads();                 // sW no longer read; reuse as reduction buffer
    float* sred = (float*)sW;        // [w][c][lr][2] = 1024 floats
    if (lg == 0) {
#pragma unroll
        for (int c = 0; c < 8; c++) {
            sred[(((w * 8 + c) * 16) + lr) * 2 + 0] = sp[c];
            sred[(((w * 8 + c) * 16) + lr) * 2 + 1] = qp[c];
        }
    }
    __syncthreads();
    if (tid < 128) {
        int c = tid >> 4, r = tid & 15;
        float s = 0.f, q = 0.f;
#pragma unroll
        for (int ww = 0; ww < 4; ww++) {
            s += sred[(((ww * 8 + c) * 16) + r) * 2 + 0];
            q += sred[(((ww * 8 + c) * 16) + r) * 2 + 1];
        }
        psumB[blockIdx.x * 128 + tid] = s;
        psqB[blockIdx.x * 128 + tid] = q;
    }
}

// ---------------- stats reduce: 128 blocks (one per feature) x 256 thr ----------------
__global__ __launch_bounds__(256) void stats_reduce_kernel(const float* __restrict__ psumB,
                                                           const float* __restrict__ psqB,
                                                           float* __restrict__ outS,
                                                           float* __restrict__ outQ) {
    int f = blockIdx.x;
    int t = threadIdx.x;
    float s = 0.f, q = 0.f;
    for (int b = t; b < GEMM_BLOCKS; b += 256) {
        s += psumB[b * 128 + f];
        q += psqB[b * 128 + f];
    }
#pragma unroll
    for (int off = 1; off < 64; off <<= 1) {
        s += __shfl_xor(s, off);
        q += __shfl_xor(q, off);
    }
    __shared__ float rs[4], rq[4];
    int w = t >> 6;
    if ((t & 63) == 0) { rs[w] = s; rq[w] = q; }
    __syncthreads();
    if (t == 0) {
        outS[f] = rs[0] + rs[1] + rs[2] + rs[3];
        outQ[f] = rq[0] + rq[1] + rq[2] + rq[3];
    }
}

// ---------------- BN1 finalize fused into W2 fold (128 blocks x 128 thr) ----------------
__global__ __launch_bounds__(128) void bnfold_kernel(const float* __restrict__ psum,
                                                     const float* __restrict__ psq,
                                                     const float* __restrict__ g,
                                                     const float* __restrict__ bt,
                                                     const float* __restrict__ W2,
                                                     const float* __restrict__ b2,
                                                     u16* __restrict__ W2ft,
                                                     float* __restrict__ b2f) {
    __shared__ float sc1[128], sh1[128];
    int k = threadIdx.x;
    int j = blockIdx.x;
    {
        float S = psum[k], Q = psq[k];
        float m = S / (float)N_NODES;
        float v = Q / (float)N_NODES - m * m;
        if (v < 0.f) v = 0.f;
        float r = rsqrtf(v + BN_EPS);
        float sc = r * g[k];
        sc1[k] = sc;
        sh1[k] = bt[k] - m * sc;
    }
    __syncthreads();
    float w = W2[k * 128 + j];
    W2ft[j * 128 + k] = f2bf(sc1[k] * w);
    float p = sh1[k] * w;
#pragma unroll
    for (int off = 1; off < 64; off <<= 1) p += __shfl_xor(p, off);
    __shared__ float r2[2];
    if ((k & 63) == 0) r2[k >> 6] = p;
    __syncthreads();
    if (k == 0) b2f[j] = b2[j] + r2[0] + r2[1];
}

// ---------------- BN2 + outer BN finalize (tiny: 1 block, 128 thr) ----------------
__global__ __launch_bounds__(128) void bnfin2_kernel(const float* __restrict__ psum,
                                                     const float* __restrict__ psq,
                                                     const float* __restrict__ g,
                                                     const float* __restrict__ bt,
                                                     const float* __restrict__ og,
                                                     const float* __restrict__ ob,
                                                     float* __restrict__ scale,
                                                     float* __restrict__ shift) {
    int f = threadIdx.x;
    float S = psum[f], Q = psq[f];
    float m = S / (float)N_NODES;
    float v = Q / (float)N_NODES - m * m;
    if (v < 0.f) v = 0.f;
    float r2 = rsqrtf(v + BN_EPS);
    float a = r2 * g[f];
    float vu = v * a * a;
    float r3 = rsqrtf(vu + BN_EPS);
    float sc = a * r3 * og[f];
    scale[f] = sc;
    shift[f] = ob[f] - m * sc;
}

// ---------------- weight prep: all layers at once ----------------
__global__ void w1_prep_kernel(const float* __restrict__ W, u16* __restrict__ Wt) {
    int q = blockIdx.x * 256 + threadIdx.x;   // 192 blocks x 256 = 3*16384
    int layer = q >> 14;
    int r = q & 16383;
    int j = r >> 7, k = r & 127;
    Wt[q] = f2bf(W[layer * 16384 + k * 128 + j]);
}

// ---------------- relu-affine, bf16 in -> bf16 out (layers 0..L-2) ----------------
__global__ __launch_bounds__(256) void relu_affine_bf16_kernel(const u16* __restrict__ Hb,
                                                               const float* __restrict__ scale,
                                                               const float* __restrict__ shift,
                                                               u16* __restrict__ xb) {
    size_t i4 = (size_t)blockIdx.x * 256 + threadIdx.x;   // 4 bf16 / thread
    int fb = ((int)(i4 & 31)) * 4;
    uint2 hv = ((const uint2*)Hb)[i4];
    float4 sc = *(const float4*)&scale[fb];
    float4 sh = *(const float4*)&shift[fb];
    float y0 = fmaxf(bflo(hv.x) * sc.x + sh.x, 0.f);
    float y1 = fmaxf(bfhi(hv.x) * sc.y + sh.y, 0.f);
    float y2 = fmaxf(bflo(hv.y) * sc.z + sh.z, 0.f);
    float y3 = fmaxf(bfhi(hv.y) * sc.w + sh.w, 0.f);
    u32 lo = (u32)f2bf(y0) | ((u32)f2bf(y1) << 16);
    u32 hi = (u32)f2bf(y2) | ((u32)f2bf(y3) << 16);
    ((uint2*)xb)[i4] = make_uint2(lo, hi);
}

// ---------------- relu-affine, final layer: fp32 in-place ----------------
__global__ __launch_bounds__(256) void relu_affine_final_kernel(float* __restrict__ H,
                                                                const float* __restrict__ scale,
                                                                const float* __restrict__ shift) {
    size_t i4 = (size_t)blockIdx.x * 256 + threadIdx.x;
    int fb = ((int)(i4 & 31)) * 4;
    float4 h = ((const float4*)H)[i4];
    float4 sc = *(const float4*)&scale[fb];
    float4 sh = *(const float4*)&shift[fb];
    float4 y;
    y.x = fmaxf(h.x * sc.x + sh.x, 0.f);
    y.y = fmaxf(h.y * sc.y + sh.y, 0.f);
    y.z = fmaxf(h.z * sc.z + sh.z, 0.f);
    y.w = fmaxf(h.w * sc.w + sh.w, 0.f);
    ((float4*)H)[i4] = y;
}

// ---------------- readout ----------------
__global__ __launch_bounds__(128) void graph_embed_part_kernel(const float* __restrict__ X,
                                                               const float* __restrict__ w,
                                                               const int* __restrict__ batch,
                                                               float* __restrict__ gpart) {
    int g = blockIdx.x;
    int sl = blockIdx.y;
    int f = threadIdx.x;
    int lo = 0, hi = N_NODES;
    while (lo < hi) { int mid = (lo + hi) >> 1; if (batch[mid] < g) lo = mid + 1; else hi = mid; }
    int s = lo;
    lo = 0; hi = N_NODES;
    while (lo < hi) { int mid = (lo + hi) >> 1; if (batch[mid] < g + 1) lo = mid + 1; else hi = mid; }
    int e = lo;
    int cnt = e - s;
    int per = (cnt + GE_SLICES - 1) / GE_SLICES;
    int rs = s + sl * per;
    int re = rs + per; if (re > e) re = e;
    float acc = 0.f;
    for (int r = rs; r < re; r++) acc += X[(size_t)r * DF + f] * w[r];
    gpart[((size_t)g * GE_SLICES + sl) * DF + f] = acc;
}

__global__ __launch_bounds__(128) void graph_embed_reduce_kernel(const float* __restrict__ gpart,
                                                                 float* __restrict__ ge) {
    int g = blockIdx.x, f = threadIdx.x;
    float a = 0.f;
#pragma unroll
    for (int s = 0; s < GE_SLICES; s++) a += gpart[((size_t)g * GE_SLICES + s) * DF + f];
    ge[g * DF + f] = a;
}

__global__ void final_fc_kernel(const float* __restrict__ ge, const float* __restrict__ fcW,
                                const float* __restrict__ fcb, float* __restrict__ out) {
    int idx = blockIdx.x * blockDim.x + threadIdx.x;  // G*C = 256
    if (idx < NG * NC) {
        int g = idx / NC, c = idx % NC;
        float acc = fcb[c];
        for (int d = 0; d < DF; d++) acc += ge[g * DF + d] * fcW[d * NC + c];
        out[idx] = acc;
    }
}

// ---------------- launcher ----------------
extern "C" void kernel_launch(void* const* d_in, const int* in_sizes, int n_in,
                              void* d_out, int out_size, void* d_ws, size_t ws_size,
                              hipStream_t stream) {
    const float* x    = (const float*)d_in[0];
    const int*   ei   = (const int*)d_in[1];
    const int*   src  = ei;
    const int*   dst  = ei + N_EDGES;
    const float* nw   = (const float*)d_in[2];
    const int*   batch= (const int*)d_in[3];
    const float* W1   = (const float*)d_in[4];
    const float* b1   = (const float*)d_in[5];
    const float* g1   = (const float*)d_in[6];
    const float* bt1  = (const float*)d_in[7];
    const float* W2   = (const float*)d_in[8];
    const float* b2   = (const float*)d_in[9];
    const float* g2   = (const float*)d_in[10];
    const float* bt2  = (const float*)d_in[11];
    const float* og   = (const float*)d_in[12];
    const float* ob   = (const float*)d_in[13];
    const float* fcW  = (const float*)d_in[14];
    const float* fcb  = (const float*)d_in[15];

    float* out_f    = (float*)d_out;
    float* node_out = out_f;                              // N*DF fp32
    float* ge       = out_f + (size_t)N_NODES * DF;       // G*DF
    float* cls      = ge + NG * DF;                       // G*C

    char* w = (char*)d_ws;
    auto alloc = [&](size_t bytes) { char* p = w; w += (bytes + 255) & ~(size_t)255; return p; };

    u16*   XB      = (u16*)alloc((size_t)N_NODES * DF * 2);     // row-major bf16 features
    u16*   AGG     = (u16*)alloc((size_t)N_NODES * DF * 2);     // bf16 agg output / bf16 h2
    u16*   H1      = (u16*)alloc((size_t)N_NODES * DF * 2);     // bf16 h1_raw
    int*   offsets = (int*)alloc((size_t)(N_NODES + 1) * 4);
    int*   adj     = (int*)alloc((size_t)N_EDGES * 4);
    float* psumB   = (float*)alloc((size_t)GEMM_BLOCKS * 128 * 4);
    float* psqB    = (float*)alloc((size_t)GEMM_BLOCKS * 128 * 4);
    float* sF      = (float*)alloc(128 * 4);
    float* qF      = (float*)alloc(128 * 4);
    u16*   W1t     = (u16*)alloc((size_t)NL * 16384 * 2);
    u16*   W2ft    = (u16*)alloc(16384 * 2);
    float* b2f     = (float*)alloc(128 * 4);
    float* scaleO  = (float*)alloc(128 * 4);
    float* shiftO  = (float*)alloc(128 * 4);
    float* gpart   = (float*)alloc((size_t)NG * GE_SLICES * DF * 4);
    int*   blkhist = (int*)alloc((size_t)NBKT * NBIN_BLOCKS * 4);
    int*   bkt_tot = (int*)alloc(NBKT * 4);
    int*   bktbase = (int*)alloc((NBKT + 1) * 4);

    // pairs buffer (12.8MB) aliases AGG (dead until first agg_kernel)
    u64* pairs = (u64*)AGG;

    // bf16 mirror of input x + weight transposes
    cvt_x_kernel<<<12500, 256, 0, stream>>>(x, XB);
    w1_prep_kernel<<<192, 256, 0, stream>>>(W1, W1t);

    // ---- CSR build: bucket sort + one-shot per-bucket offsets/adj ----
    bin_count_kernel<<<NBIN_BLOCKS, 256, 0, stream>>>(dst, blkhist);
    binscanA_kernel<<<NBKT, NBIN_BLOCKS, 0, stream>>>(blkhist, bkt_tot);
    binscanB_kernel<<<1, 128, 0, stream>>>(bkt_tot, bktbase);
    bin_scatter_kernel<<<NBIN_BLOCKS, 256, 0, stream>>>(src, dst, blkhist, bktbase, pairs);
    csr_build_kernel<<<NBKT, 1024, 0, stream>>>(pairs, bktbase, offsets, adj);

    for (int l = 0; l < NL; l++) {
        // agg = X + sum_{in-edges} X[src]   (bf16 row-major, MLP-unrolled)
        agg_kernel<<<N_NODES / 4, 256, 0, stream>>>((const u32*)XB, offsets, adj, (u32*)AGG);
        // h1_raw = agg @ W1 + b1 (bf16 out) + per-block BN1 stats
        gemm_mfma_kernel<1><<<GEMM_BLOCKS, 256, 0, stream>>>(AGG, W1t + (size_t)l * 16384,
                                                             b1 + l * DF, H1, psumB, psqB,
                                                             N_NODES);
        stats_reduce_kernel<<<128, 256, 0, stream>>>(psumB, psqB, sF, qF);
        // BN1 finalize fused into W2 fold
        bnfold_kernel<<<128, 128, 0, stream>>>(sF, qF, g1 + l * DF, bt1 + l * DF,
                                               W2 + (size_t)l * DF * DF, b2 + l * DF, W2ft, b2f);
        // h2_raw = h1_raw @ W2f + b2f (+ per-block stats); bf16 for l<2, fp32 for final
        if (l < NL - 1) {
            gemm_mfma_kernel<1><<<GEMM_BLOCKS, 256, 0, stream>>>(H1, W2ft, b2f, AGG,
                                                                 psumB, psqB, N_NODES);
        } else {
            gemm_mfma_kernel<0><<<GEMM_BLOCKS, 256, 0, stream>>>(H1, W2ft, b2f, node_out,
                                                                 psumB, psqB, N_NODES);
        }
        stats_reduce_kernel<<<128, 256, 0, stream>>>(psumB, psqB, sF, qF);
        bnfin2_kernel<<<1, 128, 0, stream>>>(sF, qF, g2 + l * DF, bt2 + l * DF,
                                             og + l * DF, ob + l * DF, scaleO, shiftO);
        if (l < NL - 1) {
            relu_affine_bf16_kernel<<<12500, 256, 0, stream>>>(AGG, scaleO, shiftO, XB);
        } else {
            relu_affine_final_kernel<<<12500, 256, 0, stream>>>(node_out, scaleO, shiftO);
        }
    }

    graph_embed_part_kernel<<<dim3(NG, GE_SLICES), 128, 0, stream>>>(node_out, nw, batch, gpart);
    graph_embed_reduce_kernel<<<NG, 128, 0, stream>>>(gpart, ge);
    final_fc_kernel<<<1, 256, 0, stream>>>(ge, fcW, fcb, cls);
}